// Round 5
// baseline (178.342 us; speedup 1.0000x reference)
//
#include <hip/hip_runtime.h>
#include <stdint.h>
#include <stddef.h>
#include <math.h>

#define DEVINL __device__ __forceinline__

typedef __attribute__((ext_vector_type(8))) __bf16 bf16x8;
typedef __attribute__((ext_vector_type(4))) float f32x4;
typedef __attribute__((ext_vector_type(4))) unsigned short us4;
typedef __attribute__((ext_vector_type(8))) unsigned short us8;

typedef __attribute__((address_space(1))) unsigned int as1_uint;
typedef __attribute__((address_space(3))) unsigned int as3_uint;

constexpr int SEQ    = 2048;
constexpr int DMODEL = 1024;
constexpr int MTOT   = 4096;    // B*L
constexpr int NQKV   = 3072;
constexpr int DKH    = 64;

// workspace layout (bytes)
constexpr size_t OFF_XBF  = 0;                                      // 8 MiB
constexpr size_t OFF_WQKV = OFF_XBF  + (size_t)MTOT * DMODEL * 2;   // 6 MiB
constexpr size_t OFF_WOUT = OFF_WQKV + (size_t)NQKV * DMODEL * 2;   // 2 MiB
constexpr size_t OFF_Q    = OFF_WOUT + (size_t)DMODEL * DMODEL * 2; // 8 MiB
constexpr size_t OFF_K    = OFF_Q    + (size_t)MTOT * DMODEL * 2;   // 8 MiB
constexpr size_t OFF_VT   = OFF_K    + (size_t)MTOT * DMODEL * 2;   // 8 MiB
constexpr size_t OFF_O    = OFF_VT   + (size_t)MTOT * DMODEL * 2;   // 8 MiB
constexpr size_t OFF_ROPE = OFF_O    + (size_t)MTOT * DMODEL * 2;   // 1 MiB

// Q pre-scale: 1/sqrt(64) * log2(e) -> softmax runs in exp2 domain
constexpr float QSCALE = 0.125f * 1.4426950408889634f;

DEVINL unsigned short f2bf(float f) {
  unsigned int u = __float_as_uint(f);
  u += 0x7fffu + ((u >> 16) & 1u);
  return (unsigned short)(u >> 16);
}

DEVINL void gld_lds16(const unsigned short* g, unsigned short* s) {
  __builtin_amdgcn_global_load_lds((as1_uint*)g, (as3_uint*)s, 16, 0, 0);
}

// ---------------- prep: fp32->bf16 converts + rope table ----------------
__global__ __launch_bounds__(256) void prep_kernel(
    const float* __restrict__ X, const float* __restrict__ Wqkv,
    const float* __restrict__ Wout, const int* __restrict__ pos,
    unsigned short* __restrict__ xbf, unsigned short* __restrict__ wqkvbf,
    unsigned short* __restrict__ woutbf, float2* __restrict__ rope) {
  const int t = blockIdx.x * 256 + threadIdx.x;
  if (t < MTOT * 32) {  // rope table: (m, pair)
    const int m = t >> 5, ip = t & 31;
    const float freq = powf(10000.0f, -(float)(2 * ip) / 64.0f);
    const float ang = (float)pos[m] * freq;
    float sv, cv;
    sincosf(ang, &sv, &cv);
    rope[t] = make_float2(cv, sv);
  }
  const int NX = MTOT * DMODEL, NW1 = NQKV * DMODEL, NW2 = DMODEL * DMODEL;
  const int e = t * 4;
  const float* src;
  unsigned short* dst;
  if (e < NX) { src = X + e; dst = xbf + e; }
  else if (e < NX + NW1) { src = Wqkv + (e - NX); dst = wqkvbf + (e - NX); }
  else if (e < NX + NW1 + NW2) { src = Wout + (e - NX - NW1); dst = woutbf + (e - NX - NW1); }
  else return;
  const float4 v = *(const float4*)src;
  us4 o = { f2bf(v.x), f2bf(v.y), f2bf(v.z), f2bf(v.w) };
  *(us4*)dst = o;
}

// ---------------- GEMM: C[m][n] = sum_k A[m][k]*B[n][k], 128x128 tile ----------------
// MODE 0: A=Xbf, B=Wqkv -> RoPE epilogue, scatter Q (pre-scaled) / K row-major,
//         V transposed per head.
// MODE 1: A=Obf,  B=Wout -> fp32 store to d_out.
template <int MODE>
__global__ __launch_bounds__(256) void gemm_kernel(
    const unsigned short* __restrict__ A, const unsigned short* __restrict__ Bw,
    unsigned short* __restrict__ q_out, unsigned short* __restrict__ k_out,
    unsigned short* __restrict__ vt_out, const float2* __restrict__ rope,
    float* __restrict__ f_out) {
  constexpr int K = DMODEL;  // 1024
  __shared__ __align__(16) unsigned short As[128 * 32];
  __shared__ __align__(16) unsigned short Bs[128 * 32];
  const int tid = threadIdx.x;
  const int l = tid & 63, w = tid >> 6;
  const int g = l >> 4, l15 = l & 15;
  const int m0 = blockIdx.y * 128, n0 = blockIdx.x * 128;
  const int wm = w >> 1, wn = w & 1;

  // staging: per wave 1KiB per instr; lane chunk = base + l*16 bytes in LDS
  const unsigned short* ag = A  + (size_t)(m0 + w * 16 + (l >> 2)) * K + (l & 3) * 8;
  const unsigned short* bg = Bw + (size_t)(n0 + w * 16 + (l >> 2)) * K + (l & 3) * 8;
  unsigned short* as0 = As + w * 512;
  unsigned short* bs0 = Bs + w * 512;

  const f32x4 zf = {0.f, 0.f, 0.f, 0.f};
  f32x4 acc[4][4];
#pragma unroll
  for (int i = 0; i < 4; ++i)
#pragma unroll
    for (int j = 0; j < 4; ++j) acc[i][j] = zf;

  for (int kt = 0; kt < K / 32; ++kt) {
    const unsigned short* a0 = ag + kt * 32;
    const unsigned short* b0 = bg + kt * 32;
    gld_lds16(a0, as0);
    gld_lds16(a0 + (size_t)64 * K, as0 + 2048);
    gld_lds16(b0, bs0);
    gld_lds16(b0 + (size_t)64 * K, bs0 + 2048);
    __syncthreads();
    bf16x8 af[4], bf[4];
#pragma unroll
    for (int i = 0; i < 4; ++i)
      af[i] = *(const bf16x8*)(As + (wm * 64 + i * 16 + l15) * 32 + g * 8);
#pragma unroll
    for (int j = 0; j < 4; ++j)
      bf[j] = *(const bf16x8*)(Bs + (wn * 64 + j * 16 + l15) * 32 + g * 8);
#pragma unroll
    for (int i = 0; i < 4; ++i)
#pragma unroll
      for (int j = 0; j < 4; ++j)
        acc[i][j] = __builtin_amdgcn_mfma_f32_16x16x32_bf16(af[i], bf[j], acc[i][j], 0, 0, 0);
    __syncthreads();
  }

  if constexpr (MODE == 0) {
    const int region = n0 >> 10;  // 0=Q 1=K 2=V (128 | 1024 region boundaries)
    if (region <= 1) {
      unsigned short* outb = (region == 0) ? q_out : k_out;
      const float qs = (region == 0) ? QSCALE : 1.0f;
#pragma unroll
      for (int i = 0; i < 4; ++i) {
        const int mb = m0 + wm * 64 + i * 16 + g * 4;
#pragma unroll
        for (int j = 0; j < 4; ++j) {
          const int n = n0 + wn * 64 + j * 16 + l15;
          const int ncol = n & 1023;
          const int ip = (n & 63) >> 1;
          const float sgn = (n & 1) ? 1.f : -1.f;
#pragma unroll
          for (int r = 0; r < 4; ++r) {
            const int m = mb + r;
            const float v = acc[i][j][r];
            const float p = __shfl_xor(v, 1);  // partner column n^1
            const float2 cs = rope[m * 32 + ip];
            const float o = (v * cs.x + sgn * p * cs.y) * qs;
            outb[(size_t)m * DMODEL + ncol] = f2bf(o);
          }
        }
      }
    } else {  // V -> transposed per head: Vt[(b*1024 + h*64 + d)][l]
#pragma unroll
      for (int i = 0; i < 4; ++i) {
        const int mb = m0 + wm * 64 + i * 16 + g * 4;
        const int b = mb >> 11;
        const int lseq = mb & 2047;
#pragma unroll
        for (int j = 0; j < 4; ++j) {
          const int n = n0 + wn * 64 + j * 16 + l15;
          const int hd = n - 2048;
          us4 o = { f2bf(acc[i][j][0]), f2bf(acc[i][j][1]), f2bf(acc[i][j][2]), f2bf(acc[i][j][3]) };
          *(us4*)(vt_out + (size_t)(b * DMODEL + hd) * SEQ + lseq) = o;
        }
      }
    }
  } else {
#pragma unroll
    for (int i = 0; i < 4; ++i) {
      const int mb = m0 + wm * 64 + i * 16 + g * 4;
#pragma unroll
      for (int j = 0; j < 4; ++j) {
        const int n = n0 + wn * 64 + j * 16 + l15;
#pragma unroll
        for (int r = 0; r < 4; ++r) f_out[(size_t)(mb + r) * DMODEL + n] = acc[i][j][r];
      }
    }
  }
}

// ---------------- causal flash attention v5 ----------------
// One 64-row q-tile per block (4 waves x 16 rows, every wave busy every iter;
// only the diagonal k-tile is partially masked). Grid (32, 32) = 1024 blocks;
// t = 31-blockIdx.x so the longest blocks (t+1 k-tiles) dispatch FIRST (LPT
// backfill balances inter-block imbalance). KVBLK=64 double-buffered, LDS
// 32 KiB with the O-transpose buffer aliased into kv -> 5 blocks/CU = 20
// waves/CU (2.5x v4's TLP). Softmax in exp2 domain (Q pre-scaled), defer-max,
// XOR-swizzle via pre-swizzled global source + linear LDS dest (rule 21).
__global__ __launch_bounds__(256) void attn_kernel(
    const unsigned short* __restrict__ Qb, const unsigned short* __restrict__ Kb,
    const unsigned short* __restrict__ Vt, unsigned short* __restrict__ Ob) {
  __shared__ __align__(16) unsigned short kv[2][2][4096];  // 32 KiB; Olds aliased post-loop
  const int tid = threadIdx.x;
  const int l = tid & 63, w = tid >> 6;
  const int g = l >> 4, q15 = l & 15;
  const int bh = blockIdx.y;
  const int b = bh >> 4, h = bh & 15;
  const int t = 31 - blockIdx.x;   // q-tile; longest work first (LPT)
  const int nkt = t + 1;
  const int qrow = t * 64 + w * 16;

  const unsigned short* qp = Qb + (size_t)(b * SEQ + qrow + q15) * DMODEL + h * DKH + g * 8;
  const bf16x8 qf0 = *(const bf16x8*)qp;
  const bf16x8 qf1 = *(const bf16x8*)(qp + 32);

  // staging source (pre-swizzled): linear LDS slot o = tid*16 (+4096) holds
  // tile element (row = o>>7, colbyte = (o&127) ^ ((row&7)<<4))
  const int rS = tid >> 3;                                        // rows 0..31 (+32)
  const int cS = (((tid & 7) * 16) ^ ((rS & 7) << 4)) >> 1;       // element col
  const unsigned short* pKg = Kb + (size_t)(b * SEQ + rS) * DMODEL + h * DKH + cS;
  const unsigned short* pVg = Vt + (size_t)(b * DMODEL + h * DKH + rS) * SEQ + cS;

  // swizzled ds_read offsets (elements), row&7 == q15&7 for all blk/d
  const int srow = (q15 & 7) << 4;
  const int oc0 = (srow ^ (g * 16)) >> 1;
  const int oc1 = (srow ^ (g * 16 + 64)) >> 1;

  const f32x4 zf = {0.f, 0.f, 0.f, 0.f};
  float mrun = -1e30f, lrun = 0.f;
  f32x4 ot[4];
#pragma unroll
  for (int d = 0; d < 4; ++d) ot[d] = zf;

  auto STAGE = [&](int bb, int k0) {
    unsigned short* lk = &kv[bb][0][0] + w * 512;  // wave-uniform base
    unsigned short* lv = &kv[bb][1][0] + w * 512;
    gld_lds16(pKg + (size_t)k0 * DMODEL, lk);
    gld_lds16(pKg + (size_t)(k0 + 32) * DMODEL, lk + 2048);
    gld_lds16(pVg + k0, lv);
    gld_lds16(pVg + (size_t)32 * SEQ + k0, lv + 2048);
  };

  STAGE(0, 0);
  __syncthreads();

  for (int i = 0; i < nkt; ++i) {
    const int cur = i & 1;
    if (i + 1 < nkt) STAGE(cur ^ 1, (i + 1) * 64);
    const bool domask = (i == t);
    const unsigned short* lkb = &kv[cur][0][0] + q15 * 64;
    const unsigned short* lvb = &kv[cur][1][0] + q15 * 64;

    float sp[4][4];
    float mt = -1e30f;
#pragma unroll
    for (int blk = 0; blk < 4; ++blk) {
      const bf16x8 kf0 = *(const bf16x8*)(lkb + blk * 1024 + oc0);
      const bf16x8 kf1 = *(const bf16x8*)(lkb + blk * 1024 + oc1);
      f32x4 c = zf;
      c = __builtin_amdgcn_mfma_f32_16x16x32_bf16(kf0, qf0, c, 0, 0, 0);
      c = __builtin_amdgcn_mfma_f32_16x16x32_bf16(kf1, qf1, c, 0, 0, 0);
#pragma unroll
      for (int r = 0; r < 4; ++r) {
        float s = c[r];  // already in exp2 domain (Q pre-scaled)
        if (domask && (blk * 16 + g * 4 + r > w * 16 + q15)) s = -1e30f;
        sp[blk][r] = s;
        mt = fmaxf(mt, s);
      }
    }
    mt = fmaxf(mt, __shfl_xor(mt, 16));
    mt = fmaxf(mt, __shfl_xor(mt, 32));

    const bool defer = __all(mt - mrun <= 8.0f);
    float mnew, alpha;
    if (defer) { mnew = mrun; alpha = 1.0f; }
    else { mnew = fmaxf(mrun, mt); alpha = exp2f(mrun - mnew); }

    float rs = 0.f;
#pragma unroll
    for (int blk = 0; blk < 4; ++blk)
#pragma unroll
      for (int r = 0; r < 4; ++r) {
        const float p = exp2f(sp[blk][r] - mnew);
        sp[blk][r] = p;
        rs += p;
      }
    rs += __shfl_xor(rs, 16);
    rs += __shfl_xor(rs, 32);
    if (defer) {
      lrun += rs;
    } else {
      lrun = lrun * alpha + rs;
      mrun = mnew;
#pragma unroll
      for (int d = 0; d < 4; ++d) ot[d] *= alpha;
    }

    // pack P pairs as bf16 (compiler fuses to v_cvt_pk_bf16_f32)
    unsigned int plo[4], phi[4];
#pragma unroll
    for (int blk = 0; blk < 4; ++blk) {
      union { __bf16 h[2]; unsigned int u; } a, bb2;
      a.h[0] = (__bf16)sp[blk][0]; a.h[1] = (__bf16)sp[blk][1];
      bb2.h[0] = (__bf16)sp[blk][2]; bb2.h[1] = (__bf16)sp[blk][3];
      plo[blk] = a.u; phi[blk] = bb2.u;
    }
    // redistribute to PV B-fragment layout
    const int srcA = (g & 1) * 32 + q15;
    const int srcB = srcA + 16;
    const bool sel = (g >> 1) != 0;
    bf16x8 pf[2];
#pragma unroll
    for (int m = 0; m < 2; ++m) {
      const unsigned int lo0A = (unsigned int)__shfl((int)plo[2 * m], srcA);
      const unsigned int lo1A = (unsigned int)__shfl((int)plo[2 * m + 1], srcA);
      const unsigned int hi0A = (unsigned int)__shfl((int)phi[2 * m], srcA);
      const unsigned int hi1A = (unsigned int)__shfl((int)phi[2 * m + 1], srcA);
      const unsigned int lo0B = (unsigned int)__shfl((int)plo[2 * m], srcB);
      const unsigned int lo1B = (unsigned int)__shfl((int)plo[2 * m + 1], srcB);
      const unsigned int hi0B = (unsigned int)__shfl((int)phi[2 * m], srcB);
      const unsigned int hi1B = (unsigned int)__shfl((int)phi[2 * m + 1], srcB);
      union { unsigned int u[4]; bf16x8 v; } pk;
      pk.u[0] = sel ? lo1A : lo0A;
      pk.u[1] = sel ? hi1A : hi0A;
      pk.u[2] = sel ? lo1B : lo0B;
      pk.u[3] = sel ? hi1B : hi0B;
      pf[m] = pk.v;
    }
    // O^T += Vt * P^T
    __builtin_amdgcn_s_setprio(1);
#pragma unroll
    for (int d = 0; d < 4; ++d) {
      const bf16x8 vf0 = *(const bf16x8*)(lvb + d * 1024 + oc0);
      const bf16x8 vf1 = *(const bf16x8*)(lvb + d * 1024 + oc1);
      ot[d] = __builtin_amdgcn_mfma_f32_16x16x32_bf16(vf0, pf[0], ot[d], 0, 0, 0);
      ot[d] = __builtin_amdgcn_mfma_f32_16x16x32_bf16(vf1, pf[1], ot[d], 0, 0, 0);
    }
    __builtin_amdgcn_s_setprio(0);
    __syncthreads();
  }

  // epilogue: O^T -> O via LDS transpose (Olds aliased into kv; loop's final
  // barrier drained all reads), /lrun, bf16 store
  unsigned short* Olds = &kv[0][0][0];  // [4][16][72] logical
  const float inv = 1.0f / lrun;
#pragma unroll
  for (int d = 0; d < 4; ++d) {
    us4 o = { f2bf(ot[d][0] * inv), f2bf(ot[d][1] * inv), f2bf(ot[d][2] * inv), f2bf(ot[d][3] * inv) };
    *(us4*)&Olds[(w * 16 + q15) * 72 + d * 16 + g * 4] = o;
  }
  __syncthreads();
  const int r = l >> 2;
  const int c = (l & 3) * 16;
  const us8 v0 = *(const us8*)&Olds[(w * 16 + r) * 72 + c];
  const us8 v1 = *(const us8*)&Olds[(w * 16 + r) * 72 + c + 8];
  unsigned short* ob = Ob + (size_t)(b * SEQ + t * 64 + w * 16 + r) * DMODEL + h * DKH + c;
  *(us8*)ob = v0;
  *(us8*)(ob + 8) = v1;
}

// ---------------- launch ----------------
extern "C" void kernel_launch(void* const* d_in, const int* in_sizes, int n_in,
                              void* d_out, int out_size, void* d_ws, size_t ws_size,
                              hipStream_t stream) {
  const float* X = (const float*)d_in[0];
  const int* pos = (const int*)d_in[1];
  const float* Wqkv = (const float*)d_in[2];
  const float* Wout = (const float*)d_in[3];
  char* ws = (char*)d_ws;
  unsigned short* xbf    = (unsigned short*)(ws + OFF_XBF);
  unsigned short* wqkvbf = (unsigned short*)(ws + OFF_WQKV);
  unsigned short* woutbf = (unsigned short*)(ws + OFF_WOUT);
  unsigned short* qb     = (unsigned short*)(ws + OFF_Q);
  unsigned short* kbuf   = (unsigned short*)(ws + OFF_K);
  unsigned short* vt     = (unsigned short*)(ws + OFF_VT);
  unsigned short* ob     = (unsigned short*)(ws + OFF_O);
  float2* rope           = (float2*)(ws + OFF_ROPE);

  prep_kernel<<<8192, 256, 0, stream>>>(X, Wqkv, Wout, pos, xbf, wqkvbf, woutbf, rope);
  gemm_kernel<0><<<dim3(NQKV / 128, MTOT / 128), 256, 0, stream>>>(
      xbf, wqkvbf, qb, kbuf, vt, rope, nullptr);
  attn_kernel<<<dim3(32, 32), 256, 0, stream>>>(qb, kbuf, vt, ob);
  gemm_kernel<1><<<dim3(DMODEL / 128, MTOT / 128), 256, 0, stream>>>(
      ob, woutbf, nullptr, nullptr, nullptr, nullptr, (float*)d_out);
}

// Round 6
// 166.671 us; speedup vs baseline: 1.0700x; 1.0700x over previous
//
#include <hip/hip_runtime.h>
#include <stdint.h>
#include <stddef.h>
#include <math.h>

#define DEVINL __device__ __forceinline__

typedef __attribute__((ext_vector_type(8))) __bf16 bf16x8;
typedef __attribute__((ext_vector_type(4))) float f32x4;
typedef __attribute__((ext_vector_type(4))) unsigned short us4;
typedef __attribute__((ext_vector_type(8))) unsigned short us8;

typedef __attribute__((address_space(1))) unsigned int as1_uint;
typedef __attribute__((address_space(3))) unsigned int as3_uint;

constexpr int SEQ    = 2048;
constexpr int DMODEL = 1024;
constexpr int MTOT   = 4096;    // B*L
constexpr int NQKV   = 3072;
constexpr int DKH    = 64;

// workspace layout (bytes)
constexpr size_t OFF_XBF  = 0;                                      // 8 MiB
constexpr size_t OFF_WQKV = OFF_XBF  + (size_t)MTOT * DMODEL * 2;   // 6 MiB
constexpr size_t OFF_WOUT = OFF_WQKV + (size_t)NQKV * DMODEL * 2;   // 2 MiB
constexpr size_t OFF_Q    = OFF_WOUT + (size_t)DMODEL * DMODEL * 2; // 8 MiB
constexpr size_t OFF_K    = OFF_Q    + (size_t)MTOT * DMODEL * 2;   // 8 MiB
constexpr size_t OFF_VT   = OFF_K    + (size_t)MTOT * DMODEL * 2;   // 8 MiB
constexpr size_t OFF_O    = OFF_VT   + (size_t)MTOT * DMODEL * 2;   // 8 MiB
constexpr size_t OFF_ROPE = OFF_O    + (size_t)MTOT * DMODEL * 2;   // 1 MiB

// Q pre-scale: 1/sqrt(64) * log2(e) -> softmax runs in exp2 domain
constexpr float QSCALE = 0.125f * 1.4426950408889634f;

DEVINL unsigned short f2bf(float f) {
  unsigned int u = __float_as_uint(f);
  u += 0x7fffu + ((u >> 16) & 1u);
  return (unsigned short)(u >> 16);
}

DEVINL void gld_lds16(const unsigned short* g, unsigned short* s) {
  __builtin_amdgcn_global_load_lds((as1_uint*)g, (as3_uint*)s, 16, 0, 0);
}

// ---------------- prep: fp32->bf16 converts + rope table ----------------
__global__ __launch_bounds__(256) void prep_kernel(
    const float* __restrict__ X, const float* __restrict__ Wqkv,
    const float* __restrict__ Wout, const int* __restrict__ pos,
    unsigned short* __restrict__ xbf, unsigned short* __restrict__ wqkvbf,
    unsigned short* __restrict__ woutbf, float2* __restrict__ rope) {
  const int t = blockIdx.x * 256 + threadIdx.x;
  if (t < MTOT * 32) {  // rope table: (m, pair)
    const int m = t >> 5, ip = t & 31;
    const float freq = powf(10000.0f, -(float)(2 * ip) / 64.0f);
    const float ang = (float)pos[m] * freq;
    float sv, cv;
    sincosf(ang, &sv, &cv);
    rope[t] = make_float2(cv, sv);
  }
  const int NX = MTOT * DMODEL, NW1 = NQKV * DMODEL, NW2 = DMODEL * DMODEL;
  const int e = t * 4;
  const float* src;
  unsigned short* dst;
  if (e < NX) { src = X + e; dst = xbf + e; }
  else if (e < NX + NW1) { src = Wqkv + (e - NX); dst = wqkvbf + (e - NX); }
  else if (e < NX + NW1 + NW2) { src = Wout + (e - NX - NW1); dst = woutbf + (e - NX - NW1); }
  else return;
  const float4 v = *(const float4*)src;
  us4 o = { f2bf(v.x), f2bf(v.y), f2bf(v.z), f2bf(v.w) };
  *(us4*)dst = o;
}

// ---------------- GEMM: C[m][n] = sum_k A[m][k]*B[n][k], 128x128 tile ----------------
// MODE 0: A=Xbf, B=Wqkv -> RoPE epilogue, scatter Q (pre-scaled) / K row-major,
//         V transposed per head.
// MODE 1: A=Obf,  B=Wout -> fp32 store to d_out.
template <int MODE>
__global__ __launch_bounds__(256) void gemm_kernel(
    const unsigned short* __restrict__ A, const unsigned short* __restrict__ Bw,
    unsigned short* __restrict__ q_out, unsigned short* __restrict__ k_out,
    unsigned short* __restrict__ vt_out, const float2* __restrict__ rope,
    float* __restrict__ f_out) {
  constexpr int K = DMODEL;  // 1024
  __shared__ __align__(16) unsigned short As[128 * 32];
  __shared__ __align__(16) unsigned short Bs[128 * 32];
  const int tid = threadIdx.x;
  const int l = tid & 63, w = tid >> 6;
  const int g = l >> 4, l15 = l & 15;
  const int m0 = blockIdx.y * 128, n0 = blockIdx.x * 128;
  const int wm = w >> 1, wn = w & 1;

  // staging: per wave 1KiB per instr; lane chunk = base + l*16 bytes in LDS
  const unsigned short* ag = A  + (size_t)(m0 + w * 16 + (l >> 2)) * K + (l & 3) * 8;
  const unsigned short* bg = Bw + (size_t)(n0 + w * 16 + (l >> 2)) * K + (l & 3) * 8;
  unsigned short* as0 = As + w * 512;
  unsigned short* bs0 = Bs + w * 512;

  const f32x4 zf = {0.f, 0.f, 0.f, 0.f};
  f32x4 acc[4][4];
#pragma unroll
  for (int i = 0; i < 4; ++i)
#pragma unroll
    for (int j = 0; j < 4; ++j) acc[i][j] = zf;

  for (int kt = 0; kt < K / 32; ++kt) {
    const unsigned short* a0 = ag + kt * 32;
    const unsigned short* b0 = bg + kt * 32;
    gld_lds16(a0, as0);
    gld_lds16(a0 + (size_t)64 * K, as0 + 2048);
    gld_lds16(b0, bs0);
    gld_lds16(b0 + (size_t)64 * K, bs0 + 2048);
    __syncthreads();
    bf16x8 af[4], bf[4];
#pragma unroll
    for (int i = 0; i < 4; ++i)
      af[i] = *(const bf16x8*)(As + (wm * 64 + i * 16 + l15) * 32 + g * 8);
#pragma unroll
    for (int j = 0; j < 4; ++j)
      bf[j] = *(const bf16x8*)(Bs + (wn * 64 + j * 16 + l15) * 32 + g * 8);
#pragma unroll
    for (int i = 0; i < 4; ++i)
#pragma unroll
      for (int j = 0; j < 4; ++j)
        acc[i][j] = __builtin_amdgcn_mfma_f32_16x16x32_bf16(af[i], bf[j], acc[i][j], 0, 0, 0);
    __syncthreads();
  }

  if constexpr (MODE == 0) {
    const int region = n0 >> 10;  // 0=Q 1=K 2=V (128 | 1024 region boundaries)
    if (region <= 1) {
      unsigned short* outb = (region == 0) ? q_out : k_out;
      const float qs = (region == 0) ? QSCALE : 1.0f;
#pragma unroll
      for (int i = 0; i < 4; ++i) {
        const int mb = m0 + wm * 64 + i * 16 + g * 4;
#pragma unroll
        for (int j = 0; j < 4; ++j) {
          const int n = n0 + wn * 64 + j * 16 + l15;
          const int ncol = n & 1023;
          const int ip = (n & 63) >> 1;
          const float sgn = (n & 1) ? 1.f : -1.f;
#pragma unroll
          for (int r = 0; r < 4; ++r) {
            const int m = mb + r;
            const float v = acc[i][j][r];
            const float p = __shfl_xor(v, 1);  // partner column n^1
            const float2 cs = rope[m * 32 + ip];
            const float o = (v * cs.x + sgn * p * cs.y) * qs;
            outb[(size_t)m * DMODEL + ncol] = f2bf(o);
          }
        }
      }
    } else {  // V -> transposed per head: Vt[(b*1024 + h*64 + d)][l]
#pragma unroll
      for (int i = 0; i < 4; ++i) {
        const int mb = m0 + wm * 64 + i * 16 + g * 4;
        const int b = mb >> 11;
        const int lseq = mb & 2047;
#pragma unroll
        for (int j = 0; j < 4; ++j) {
          const int n = n0 + wn * 64 + j * 16 + l15;
          const int hd = n - 2048;
          us4 o = { f2bf(acc[i][j][0]), f2bf(acc[i][j][1]), f2bf(acc[i][j][2]), f2bf(acc[i][j][3]) };
          *(us4*)(vt_out + (size_t)(b * DMODEL + hd) * SEQ + lseq) = o;
        }
      }
    }
  } else {
#pragma unroll
    for (int i = 0; i < 4; ++i) {
      const int mb = m0 + wm * 64 + i * 16 + g * 4;
#pragma unroll
      for (int j = 0; j < 4; ++j) {
        const int n = n0 + wn * 64 + j * 16 + l15;
#pragma unroll
        for (int r = 0; r < 4; ++r) f_out[(size_t)(mb + r) * DMODEL + n] = acc[i][j][r];
      }
    }
  }
}

// ---------------- causal flash attention v6 ----------------
// v2 pairing structure (block j: sequential phases (31-j, j), 4 waves x 16
// q-rows, uniform 33 iterations, 512 blocks) + T3/T4-lite pipeline: K/V
// triple-buffered, prefetch depth 2, counted `s_waitcnt vmcnt(4)` + raw
// s_barrier per iteration (each wave certifies ITS tile-(i+1) loads before
// the barrier; tile-(i+2) loads stay in flight across it). sched_barrier(0)
// after the barrier stops hipcc hoisting next-iter ds_reads above it.
// Softmax in exp2 domain (Q pre-scaled by 0.125*log2e), defer-max THR=8,
// XOR-swizzle via pre-swizzled global source + linear LDS dest (rule 21).
__global__ __launch_bounds__(256) void attn_kernel(
    const unsigned short* __restrict__ Qb, const unsigned short* __restrict__ Kb,
    const unsigned short* __restrict__ Vt, unsigned short* __restrict__ Ob) {
  __shared__ __align__(16) unsigned short kv[3][2][4096];  // 48 KiB triple buffer
  __shared__ __align__(16) unsigned short Olds[4][16][72]; // 9 KiB
  const int tid = threadIdx.x;
  const int l = tid & 63, w = tid >> 6;
  const int g = l >> 4, q15 = l & 15;
  const int bh = blockIdx.y;
  const int b = bh >> 4, h = bh & 15;
  const int tA = 31 - blockIdx.x;   // long phase q-tile
  const int tB = blockIdx.x;        // short phase q-tile

  // Q fragments for both phases (16 q-rows per wave)
  const unsigned short* qpA = Qb + (size_t)(b * SEQ + tA * 64 + w * 16 + q15) * DMODEL + h * DKH + g * 8;
  const unsigned short* qpB = Qb + (size_t)(b * SEQ + tB * 64 + w * 16 + q15) * DMODEL + h * DKH + g * 8;
  const bf16x8 qA0 = *(const bf16x8*)qpA, qA1 = *(const bf16x8*)(qpA + 32);
  const bf16x8 qB0 = *(const bf16x8*)qpB, qB1 = *(const bf16x8*)(qpB + 32);
  const int qselA = tA * 64 + w * 16 + q15;
  const int qselB = tB * 64 + w * 16 + q15;

  // staging source (pre-swizzled): linear LDS slot o = tid*16 (+4096) holds
  // tile element (row = o>>7, colbyte = (o&127) ^ ((row&7)<<4))
  const int rS = tid >> 3;                                        // rows 0..31 (+32)
  const int cS = (((tid & 7) * 16) ^ ((rS & 7) << 4)) >> 1;       // element col
  const unsigned short* pKg = Kb + (size_t)(b * SEQ + rS) * DMODEL + h * DKH + cS;
  const unsigned short* pVg = Vt + (size_t)(b * DMODEL + h * DKH + rS) * SEQ + cS;

  // swizzled ds_read offsets (elements), row&7 == q15&7 for all blk/d
  const int srow = (q15 & 7) << 4;
  const int oc0 = (srow ^ (g * 16)) >> 1;
  const int oc1 = (srow ^ (g * 16 + 64)) >> 1;

  const f32x4 zf = {0.f, 0.f, 0.f, 0.f};
  float mrun = -1e30f, lrun = 0.f;
  f32x4 ot[4];
#pragma unroll
  for (int d = 0; d < 4; ++d) ot[d] = zf;

  auto STAGE = [&](int bb, int k0) {
    unsigned short* lk = &kv[bb][0][0] + w * 512;  // wave-uniform base
    unsigned short* lv = &kv[bb][1][0] + w * 512;
    gld_lds16(pKg + (size_t)k0 * DMODEL, lk);
    gld_lds16(pKg + (size_t)(k0 + 32) * DMODEL, lk + 2048);
    gld_lds16(pVg + k0, lv);
    gld_lds16(pVg + (size_t)32 * SEQ + k0, lv + 2048);
  };

  auto STORE = [&](int qt) {
    const float inv = 1.0f / lrun;
#pragma unroll
    for (int d = 0; d < 4; ++d) {
      us4 o = { f2bf(ot[d][0] * inv), f2bf(ot[d][1] * inv), f2bf(ot[d][2] * inv), f2bf(ot[d][3] * inv) };
      *(us4*)&Olds[w][q15][d * 16 + g * 4] = o;
    }
    // lgkm-only barrier: do NOT drain vmcnt (prefetches stay in flight)
    asm volatile("s_waitcnt lgkmcnt(0)" ::: "memory");
    __builtin_amdgcn_s_barrier();
    __builtin_amdgcn_sched_barrier(0);
    const int r = l >> 2;
    const int c = (l & 3) * 16;
    const us8 v0 = *(const us8*)&Olds[w][r][c];
    const us8 v1 = *(const us8*)&Olds[w][r][c + 8];
    unsigned short* ob = Ob + (size_t)(b * SEQ + qt * 64 + w * 16 + r) * DMODEL + h * DKH + c;
    *(us8*)ob = v0;
    *(us8*)(ob + 8) = v1;
  };

  auto KN = [&](int j) { return (j <= tA) ? j : (j - tA - 1); };

  STAGE(0, 0);
  STAGE(1, KN(1) * 64);
  asm volatile("s_waitcnt vmcnt(4)" ::: "memory");
  __builtin_amdgcn_s_barrier();
  __builtin_amdgcn_sched_barrier(0);

  for (int i = 0; i < 33; ++i) {
    const int cur = i % 3;
    const bool phA = (i <= tA);
    const int kt = phA ? i : (i - tA - 1);
    if (i + 2 < 33) STAGE((i + 2) % 3, KN(i + 2) * 64);

    const bf16x8 qf0 = phA ? qA0 : qB0;
    const bf16x8 qf1 = phA ? qA1 : qB1;
    const bool domask = phA ? (kt == tA) : (kt == tB);
    const int qsel = phA ? qselA : qselB;
    const int kb0 = kt * 64;
    const unsigned short* lkb = &kv[cur][0][0] + q15 * 64;
    const unsigned short* lvb = &kv[cur][1][0] + q15 * 64;

    float sp[4][4];
    float mt = -1e30f;
#pragma unroll
    for (int blk = 0; blk < 4; ++blk) {
      const bf16x8 kf0 = *(const bf16x8*)(lkb + blk * 1024 + oc0);
      const bf16x8 kf1 = *(const bf16x8*)(lkb + blk * 1024 + oc1);
      f32x4 c = zf;
      c = __builtin_amdgcn_mfma_f32_16x16x32_bf16(kf0, qf0, c, 0, 0, 0);
      c = __builtin_amdgcn_mfma_f32_16x16x32_bf16(kf1, qf1, c, 0, 0, 0);
#pragma unroll
      for (int r = 0; r < 4; ++r) {
        float s = c[r];  // already in exp2 domain (Q pre-scaled)
        if (domask && (kb0 + blk * 16 + g * 4 + r > qsel)) s = -1e30f;
        sp[blk][r] = s;
        mt = fmaxf(mt, s);
      }
    }
    mt = fmaxf(mt, __shfl_xor(mt, 16));
    mt = fmaxf(mt, __shfl_xor(mt, 32));

    const bool defer = __all(mt - mrun <= 8.0f);
    float mnew, alpha;
    if (defer) { mnew = mrun; alpha = 1.0f; }
    else { mnew = fmaxf(mrun, mt); alpha = exp2f(mrun - mnew); }

    float rs = 0.f;
#pragma unroll
    for (int blk = 0; blk < 4; ++blk)
#pragma unroll
      for (int r = 0; r < 4; ++r) {
        const float p = exp2f(sp[blk][r] - mnew);
        sp[blk][r] = p;
        rs += p;
      }
    rs += __shfl_xor(rs, 16);
    rs += __shfl_xor(rs, 32);
    if (defer) {
      lrun += rs;
    } else {
      lrun = lrun * alpha + rs;
      mrun = mnew;
#pragma unroll
      for (int d = 0; d < 4; ++d) ot[d] *= alpha;
    }

    // pack P pairs as bf16 (compiler fuses to v_cvt_pk_bf16_f32)
    unsigned int plo[4], phi[4];
#pragma unroll
    for (int blk = 0; blk < 4; ++blk) {
      union { __bf16 h[2]; unsigned int u; } a, bb2;
      a.h[0] = (__bf16)sp[blk][0]; a.h[1] = (__bf16)sp[blk][1];
      bb2.h[0] = (__bf16)sp[blk][2]; bb2.h[1] = (__bf16)sp[blk][3];
      plo[blk] = a.u; phi[blk] = bb2.u;
    }
    // redistribute to PV B-fragment layout
    const int srcA = (g & 1) * 32 + q15;
    const int srcB = srcA + 16;
    const bool sel = (g >> 1) != 0;
    bf16x8 pf[2];
#pragma unroll
    for (int m = 0; m < 2; ++m) {
      const unsigned int lo0A = (unsigned int)__shfl((int)plo[2 * m], srcA);
      const unsigned int lo1A = (unsigned int)__shfl((int)plo[2 * m + 1], srcA);
      const unsigned int hi0A = (unsigned int)__shfl((int)phi[2 * m], srcA);
      const unsigned int hi1A = (unsigned int)__shfl((int)phi[2 * m + 1], srcA);
      const unsigned int lo0B = (unsigned int)__shfl((int)plo[2 * m], srcB);
      const unsigned int lo1B = (unsigned int)__shfl((int)plo[2 * m + 1], srcB);
      const unsigned int hi0B = (unsigned int)__shfl((int)phi[2 * m], srcB);
      const unsigned int hi1B = (unsigned int)__shfl((int)phi[2 * m + 1], srcB);
      union { unsigned int u[4]; bf16x8 v; } pk;
      pk.u[0] = sel ? lo1A : lo0A;
      pk.u[1] = sel ? hi1A : hi0A;
      pk.u[2] = sel ? lo1B : lo0B;
      pk.u[3] = sel ? hi1B : hi0B;
      pf[m] = pk.v;
    }
    // O^T += Vt * P^T
    __builtin_amdgcn_s_setprio(1);
#pragma unroll
    for (int d = 0; d < 4; ++d) {
      const bf16x8 vf0 = *(const bf16x8*)(lvb + d * 1024 + oc0);
      const bf16x8 vf1 = *(const bf16x8*)(lvb + d * 1024 + oc1);
      ot[d] = __builtin_amdgcn_mfma_f32_16x16x32_bf16(vf0, pf[0], ot[d], 0, 0, 0);
      ot[d] = __builtin_amdgcn_mfma_f32_16x16x32_bf16(vf1, pf[1], ot[d], 0, 0, 0);
    }
    __builtin_amdgcn_s_setprio(0);

    if (phA && kt == tA) {  // phase switch: flush A, reset state
      STORE(tA);
      mrun = -1e30f; lrun = 0.f;
#pragma unroll
      for (int d = 0; d < 4; ++d) ot[d] = zf;
    }

    // counted-vmcnt barrier: tile i+1 certified done per-wave; tile i+2 loads
    // (the 4 newest) stay in flight across the barrier.
    if (i + 2 < 33) {
      asm volatile("s_waitcnt vmcnt(4)" ::: "memory");
    } else {
      asm volatile("s_waitcnt vmcnt(0)" ::: "memory");
    }
    __builtin_amdgcn_s_barrier();
    __builtin_amdgcn_sched_barrier(0);
  }
  STORE(tB);
}

// ---------------- launch ----------------
extern "C" void kernel_launch(void* const* d_in, const int* in_sizes, int n_in,
                              void* d_out, int out_size, void* d_ws, size_t ws_size,
                              hipStream_t stream) {
  const float* X = (const float*)d_in[0];
  const int* pos = (const int*)d_in[1];
  const float* Wqkv = (const float*)d_in[2];
  const float* Wout = (const float*)d_in[3];
  char* ws = (char*)d_ws;
  unsigned short* xbf    = (unsigned short*)(ws + OFF_XBF);
  unsigned short* wqkvbf = (unsigned short*)(ws + OFF_WQKV);
  unsigned short* woutbf = (unsigned short*)(ws + OFF_WOUT);
  unsigned short* qb     = (unsigned short*)(ws + OFF_Q);
  unsigned short* kbuf   = (unsigned short*)(ws + OFF_K);
  unsigned short* vt     = (unsigned short*)(ws + OFF_VT);
  unsigned short* ob     = (unsigned short*)(ws + OFF_O);
  float2* rope           = (float2*)(ws + OFF_ROPE);

  prep_kernel<<<8192, 256, 0, stream>>>(X, Wqkv, Wout, pos, xbf, wqkvbf, woutbf, rope);
  gemm_kernel<0><<<dim3(NQKV / 128, MTOT / 128), 256, 0, stream>>>(
      xbf, wqkvbf, qb, kbuf, vt, rope, nullptr);
  attn_kernel<<<dim3(16, 32), 256, 0, stream>>>(qb, kbuf, vt, ob);
  gemm_kernel<1><<<dim3(DMODEL / 128, MTOT / 128), 256, 0, stream>>>(
      ob, woutbf, nullptr, nullptr, nullptr, nullptr, (float*)d_out);
}

// Round 7
// 164.746 us; speedup vs baseline: 1.0825x; 1.0117x over previous
//
#include <hip/hip_runtime.h>
#include <stdint.h>
#include <stddef.h>
#include <math.h>

#define DEVINL __device__ __forceinline__

typedef __attribute__((ext_vector_type(8))) __bf16 bf16x8;
typedef __attribute__((ext_vector_type(4))) float f32x4;
typedef __attribute__((ext_vector_type(4))) unsigned short us4;
typedef __attribute__((ext_vector_type(8))) unsigned short us8;

typedef __attribute__((address_space(1))) unsigned int as1_uint;
typedef __attribute__((address_space(3))) unsigned int as3_uint;

constexpr int SEQ    = 2048;
constexpr int DMODEL = 1024;
constexpr int MTOT   = 4096;    // B*L
constexpr int NQKV   = 3072;
constexpr int DKH    = 64;

// workspace layout (bytes)
constexpr size_t OFF_XBF  = 0;                                      // 8 MiB
constexpr size_t OFF_WQKV = OFF_XBF  + (size_t)MTOT * DMODEL * 2;   // 6 MiB
constexpr size_t OFF_WOUT = OFF_WQKV + (size_t)NQKV * DMODEL * 2;   // 2 MiB
constexpr size_t OFF_Q    = OFF_WOUT + (size_t)DMODEL * DMODEL * 2; // 8 MiB
constexpr size_t OFF_K    = OFF_Q    + (size_t)MTOT * DMODEL * 2;   // 8 MiB
constexpr size_t OFF_VT   = OFF_K    + (size_t)MTOT * DMODEL * 2;   // 8 MiB
constexpr size_t OFF_O    = OFF_VT   + (size_t)MTOT * DMODEL * 2;   // 8 MiB
constexpr size_t OFF_ROPE = OFF_O    + (size_t)MTOT * DMODEL * 2;   // 1 MiB

// Q pre-scale: 1/sqrt(64) * log2(e) -> softmax runs in exp2 domain
constexpr float QSCALE = 0.125f * 1.4426950408889634f;

DEVINL unsigned short f2bf(float f) {
  unsigned int u = __float_as_uint(f);
  u += 0x7fffu + ((u >> 16) & 1u);
  return (unsigned short)(u >> 16);
}

DEVINL void gld_lds16(const unsigned short* g, unsigned short* s) {
  __builtin_amdgcn_global_load_lds((as1_uint*)g, (as3_uint*)s, 16, 0, 0);
}

// ---------------- prep: fp32->bf16 converts + rope table ----------------
__global__ __launch_bounds__(256) void prep_kernel(
    const float* __restrict__ X, const float* __restrict__ Wqkv,
    const float* __restrict__ Wout, const int* __restrict__ pos,
    unsigned short* __restrict__ xbf, unsigned short* __restrict__ wqkvbf,
    unsigned short* __restrict__ woutbf, float2* __restrict__ rope) {
  const int t = blockIdx.x * 256 + threadIdx.x;
  if (t < MTOT * 32) {  // rope table: (m, pair)
    const int m = t >> 5, ip = t & 31;
    const float freq = powf(10000.0f, -(float)(2 * ip) / 64.0f);
    const float ang = (float)pos[m] * freq;
    float sv, cv;
    sincosf(ang, &sv, &cv);
    rope[t] = make_float2(cv, sv);
  }
  const int NX = MTOT * DMODEL, NW1 = NQKV * DMODEL, NW2 = DMODEL * DMODEL;
  const int e = t * 4;
  const float* src;
  unsigned short* dst;
  if (e < NX) { src = X + e; dst = xbf + e; }
  else if (e < NX + NW1) { src = Wqkv + (e - NX); dst = wqkvbf + (e - NX); }
  else if (e < NX + NW1 + NW2) { src = Wout + (e - NX - NW1); dst = woutbf + (e - NX - NW1); }
  else return;
  const float4 v = *(const float4*)src;
  us4 o = { f2bf(v.x), f2bf(v.y), f2bf(v.z), f2bf(v.w) };
  *(us4*)dst = o;
}

// ---------------- GEMM: C[m][n] = sum_k A[m][k]*B[n][k], 128x128 tile ----------------
// MODE 0: A=Xbf, B=Wqkv -> RoPE epilogue, scatter Q (pre-scaled) / K row-major,
//         V transposed per head.
// MODE 1: A=Obf,  B=Wout -> fp32 store to d_out.
template <int MODE>
__global__ __launch_bounds__(256) void gemm_kernel(
    const unsigned short* __restrict__ A, const unsigned short* __restrict__ Bw,
    unsigned short* __restrict__ q_out, unsigned short* __restrict__ k_out,
    unsigned short* __restrict__ vt_out, const float2* __restrict__ rope,
    float* __restrict__ f_out) {
  constexpr int K = DMODEL;  // 1024
  __shared__ __align__(16) unsigned short As[128 * 32];
  __shared__ __align__(16) unsigned short Bs[128 * 32];
  const int tid = threadIdx.x;
  const int l = tid & 63, w = tid >> 6;
  const int g = l >> 4, l15 = l & 15;
  const int m0 = blockIdx.y * 128, n0 = blockIdx.x * 128;
  const int wm = w >> 1, wn = w & 1;

  // staging: per wave 1KiB per instr; lane chunk = base + l*16 bytes in LDS
  const unsigned short* ag = A  + (size_t)(m0 + w * 16 + (l >> 2)) * K + (l & 3) * 8;
  const unsigned short* bg = Bw + (size_t)(n0 + w * 16 + (l >> 2)) * K + (l & 3) * 8;
  unsigned short* as0 = As + w * 512;
  unsigned short* bs0 = Bs + w * 512;

  const f32x4 zf = {0.f, 0.f, 0.f, 0.f};
  f32x4 acc[4][4];
#pragma unroll
  for (int i = 0; i < 4; ++i)
#pragma unroll
    for (int j = 0; j < 4; ++j) acc[i][j] = zf;

  for (int kt = 0; kt < K / 32; ++kt) {
    const unsigned short* a0 = ag + kt * 32;
    const unsigned short* b0 = bg + kt * 32;
    gld_lds16(a0, as0);
    gld_lds16(a0 + (size_t)64 * K, as0 + 2048);
    gld_lds16(b0, bs0);
    gld_lds16(b0 + (size_t)64 * K, bs0 + 2048);
    __syncthreads();
    bf16x8 af[4], bf[4];
#pragma unroll
    for (int i = 0; i < 4; ++i)
      af[i] = *(const bf16x8*)(As + (wm * 64 + i * 16 + l15) * 32 + g * 8);
#pragma unroll
    for (int j = 0; j < 4; ++j)
      bf[j] = *(const bf16x8*)(Bs + (wn * 64 + j * 16 + l15) * 32 + g * 8);
#pragma unroll
    for (int i = 0; i < 4; ++i)
#pragma unroll
      for (int j = 0; j < 4; ++j)
        acc[i][j] = __builtin_amdgcn_mfma_f32_16x16x32_bf16(af[i], bf[j], acc[i][j], 0, 0, 0);
    __syncthreads();
  }

  if constexpr (MODE == 0) {
    const int region = n0 >> 10;  // 0=Q 1=K 2=V (128 | 1024 region boundaries)
    if (region <= 1) {
      unsigned short* outb = (region == 0) ? q_out : k_out;
      const float qs = (region == 0) ? QSCALE : 1.0f;
#pragma unroll
      for (int i = 0; i < 4; ++i) {
        const int mb = m0 + wm * 64 + i * 16 + g * 4;
#pragma unroll
        for (int j = 0; j < 4; ++j) {
          const int n = n0 + wn * 64 + j * 16 + l15;
          const int ncol = n & 1023;
          const int ip = (n & 63) >> 1;
          const float sgn = (n & 1) ? 1.f : -1.f;
#pragma unroll
          for (int r = 0; r < 4; ++r) {
            const int m = mb + r;
            const float v = acc[i][j][r];
            const float p = __shfl_xor(v, 1);  // partner column n^1
            const float2 cs = rope[m * 32 + ip];
            const float o = (v * cs.x + sgn * p * cs.y) * qs;
            outb[(size_t)m * DMODEL + ncol] = f2bf(o);
          }
        }
      }
    } else {  // V -> transposed per head: Vt[(b*1024 + h*64 + d)][l]
#pragma unroll
      for (int i = 0; i < 4; ++i) {
        const int mb = m0 + wm * 64 + i * 16 + g * 4;
        const int b = mb >> 11;
        const int lseq = mb & 2047;
#pragma unroll
        for (int j = 0; j < 4; ++j) {
          const int n = n0 + wn * 64 + j * 16 + l15;
          const int hd = n - 2048;
          us4 o = { f2bf(acc[i][j][0]), f2bf(acc[i][j][1]), f2bf(acc[i][j][2]), f2bf(acc[i][j][3]) };
          *(us4*)(vt_out + (size_t)(b * DMODEL + hd) * SEQ + lseq) = o;
        }
      }
    }
  } else {
#pragma unroll
    for (int i = 0; i < 4; ++i) {
      const int mb = m0 + wm * 64 + i * 16 + g * 4;
#pragma unroll
      for (int j = 0; j < 4; ++j) {
        const int n = n0 + wn * 64 + j * 16 + l15;
#pragma unroll
        for (int r = 0; r < 4; ++r) f_out[(size_t)(mb + r) * DMODEL + n] = acc[i][j][r];
      }
    }
  }
}

// ---------------- causal flash attention v7 ----------------
// v2 structure (block j: sequential phases (31-j, j), 4 waves x 16 q-rows,
// uniform 33 iterations, KVBLK=64 double-buffered, __syncthreads) + DUAL
// independent softmax chains per wave: chain A = k 0..31, chain B = k 32..63
// of each tile, each with its own online state (m,l,O^T), merged at STORE.
// Doubles per-wave ILP: each chain's MFMA/shuffle/exp2 latency hides under
// the other chain's work. m init = -1e20 so a fully-masked chain defers and
// exp2(-1e30 - (-1e20)) underflows to 0 (not the exp2(0)=1 poison).
__global__ __launch_bounds__(256) void attn_kernel(
    const unsigned short* __restrict__ Qb, const unsigned short* __restrict__ Kb,
    const unsigned short* __restrict__ Vt, unsigned short* __restrict__ Ob) {
  __shared__ __align__(16) unsigned short kv[2][2][4096];  // [buf][K/V][64*64]
  __shared__ __align__(16) unsigned short Olds[4][16][72];
  const int tid = threadIdx.x;
  const int l = tid & 63, w = tid >> 6;
  const int g = l >> 4, q15 = l & 15;
  const int bh = blockIdx.y;
  const int b = bh >> 4, h = bh & 15;
  const int tA = 31 - blockIdx.x;   // long phase q-tile
  const int tB = blockIdx.x;        // short phase q-tile

  // Q fragments for both phases (16 q-rows per wave)
  const unsigned short* qpA = Qb + (size_t)(b * SEQ + tA * 64 + w * 16 + q15) * DMODEL + h * DKH + g * 8;
  const unsigned short* qpB = Qb + (size_t)(b * SEQ + tB * 64 + w * 16 + q15) * DMODEL + h * DKH + g * 8;
  const bf16x8 qA0 = *(const bf16x8*)qpA, qA1 = *(const bf16x8*)(qpA + 32);
  const bf16x8 qB0 = *(const bf16x8*)qpB, qB1 = *(const bf16x8*)(qpB + 32);
  const int qselA = tA * 64 + w * 16 + q15;
  const int qselB = tB * 64 + w * 16 + q15;

  // staging source (pre-swizzled): linear LDS slot o = tid*16 (+4096) holds
  // tile element (row = o>>7, colbyte = (o&127) ^ ((row&7)<<4))
  const int rS = tid >> 3;                                        // rows 0..31 (+32)
  const int cS = (((tid & 7) * 16) ^ ((rS & 7) << 4)) >> 1;       // element col
  const unsigned short* pKg = Kb + (size_t)(b * SEQ + rS) * DMODEL + h * DKH + cS;
  const unsigned short* pVg = Vt + (size_t)(b * DMODEL + h * DKH + rS) * SEQ + cS;

  // swizzled ds_read offsets (elements), row&7 == q15&7 for all blk/d
  const int srow = (q15 & 7) << 4;
  const int oc0 = (srow ^ (g * 16)) >> 1;
  const int oc1 = (srow ^ (g * 16 + 64)) >> 1;

  const f32x4 zf = {0.f, 0.f, 0.f, 0.f};
  // dual-chain online-softmax state
  float mrA = -1e20f, lrA = 0.f, mrB = -1e20f, lrB = 0.f;
  f32x4 otA[4], otB[4];
#pragma unroll
  for (int d = 0; d < 4; ++d) { otA[d] = zf; otB[d] = zf; }

  auto STAGE = [&](int bb, int k0) {
    unsigned short* lk = &kv[bb][0][0] + w * 512;  // wave-uniform base
    unsigned short* lv = &kv[bb][1][0] + w * 512;
    gld_lds16(pKg + (size_t)k0 * DMODEL, lk);
    gld_lds16(pKg + (size_t)(k0 + 32) * DMODEL, lk + 2048);
    gld_lds16(pVg + k0, lv);
    gld_lds16(pVg + (size_t)32 * SEQ + k0, lv + 2048);
  };

  auto STORE = [&](int qt) {
    // merge the two chains, then transpose via LDS and store bf16
    const float m = fmaxf(mrA, mrB);
    const float wA = exp2f(mrA - m), wB = exp2f(mrB - m);
    const float inv = 1.0f / (lrA * wA + lrB * wB);
#pragma unroll
    for (int d = 0; d < 4; ++d) {
      const f32x4 o4 = otA[d] * wA + otB[d] * wB;
      us4 o = { f2bf(o4[0] * inv), f2bf(o4[1] * inv), f2bf(o4[2] * inv), f2bf(o4[3] * inv) };
      *(us4*)&Olds[w][q15][d * 16 + g * 4] = o;
    }
    __syncthreads();
    const int r = l >> 2;
    const int c = (l & 3) * 16;
    const us8 v0 = *(const us8*)&Olds[w][r][c];
    const us8 v1 = *(const us8*)&Olds[w][r][c + 8];
    unsigned short* ob = Ob + (size_t)(b * SEQ + qt * 64 + w * 16 + r) * DMODEL + h * DKH + c;
    *(us8*)ob = v0;
    *(us8*)(ob + 8) = v1;
  };

  STAGE(0, 0);
  __syncthreads();

  for (int i = 0; i < 33; ++i) {
    const int cur = i & 1;
    const bool phA = (i <= tA);
    const int kt = phA ? i : (i - tA - 1);
    if (i + 1 < 33) {
      const int kn = (i + 1 <= tA) ? (i + 1) : (i - tA);
      STAGE(cur ^ 1, kn * 64);
    }
    const bf16x8 qf0 = phA ? qA0 : qB0;
    const bf16x8 qf1 = phA ? qA1 : qB1;
    const bool domask = phA ? (kt == tA) : (kt == tB);
    const int qsel = phA ? qselA : qselB;
    const int kb0 = kt * 64;
    const unsigned short* lkb = &kv[cur][0][0] + q15 * 64;
    const unsigned short* lvb = &kv[cur][1][0] + q15 * 64;

    // QK^T both chains (chain A: blk 0-1 = k 0..31; chain B: blk 2-3 = k 32..63)
    float sp[4][4];
    float mtA = -1e30f, mtB = -1e30f;
#pragma unroll
    for (int blk = 0; blk < 4; ++blk) {
      const bf16x8 kf0 = *(const bf16x8*)(lkb + blk * 1024 + oc0);
      const bf16x8 kf1 = *(const bf16x8*)(lkb + blk * 1024 + oc1);
      f32x4 c = zf;
      c = __builtin_amdgcn_mfma_f32_16x16x32_bf16(kf0, qf0, c, 0, 0, 0);
      c = __builtin_amdgcn_mfma_f32_16x16x32_bf16(kf1, qf1, c, 0, 0, 0);
#pragma unroll
      for (int r = 0; r < 4; ++r) {
        float s = c[r];  // already in exp2 domain (Q pre-scaled)
        if (domask && (kb0 + blk * 16 + g * 4 + r > qsel)) s = -1e30f;
        sp[blk][r] = s;
        if (blk < 2) mtA = fmaxf(mtA, s); else mtB = fmaxf(mtB, s);
      }
    }
    mtA = fmaxf(mtA, __shfl_xor(mtA, 16));
    mtA = fmaxf(mtA, __shfl_xor(mtA, 32));
    mtB = fmaxf(mtB, __shfl_xor(mtB, 16));
    mtB = fmaxf(mtB, __shfl_xor(mtB, 32));

    const bool deferA = __all(mtA - mrA <= 8.0f);
    const bool deferB = __all(mtB - mrB <= 8.0f);
    float mnA, alA, mnB, alB;
    if (deferA) { mnA = mrA; alA = 1.0f; }
    else { mnA = fmaxf(mrA, mtA); alA = exp2f(mrA - mnA); }
    if (deferB) { mnB = mrB; alB = 1.0f; }
    else { mnB = fmaxf(mrB, mtB); alB = exp2f(mrB - mnB); }

    float rsA = 0.f, rsB = 0.f;
#pragma unroll
    for (int blk = 0; blk < 2; ++blk)
#pragma unroll
      for (int r = 0; r < 4; ++r) {
        const float p = exp2f(sp[blk][r] - mnA);
        sp[blk][r] = p;
        rsA += p;
      }
#pragma unroll
    for (int blk = 2; blk < 4; ++blk)
#pragma unroll
      for (int r = 0; r < 4; ++r) {
        const float p = exp2f(sp[blk][r] - mnB);
        sp[blk][r] = p;
        rsB += p;
      }
    rsA += __shfl_xor(rsA, 16);
    rsA += __shfl_xor(rsA, 32);
    rsB += __shfl_xor(rsB, 16);
    rsB += __shfl_xor(rsB, 32);
    if (deferA) { lrA += rsA; }
    else {
      lrA = lrA * alA + rsA; mrA = mnA;
#pragma unroll
      for (int d = 0; d < 4; ++d) otA[d] *= alA;
    }
    if (deferB) { lrB += rsB; }
    else {
      lrB = lrB * alB + rsB; mrB = mnB;
#pragma unroll
      for (int d = 0; d < 4; ++d) otB[d] *= alB;
    }

    // pack P pairs as bf16 (compiler fuses to v_cvt_pk_bf16_f32)
    unsigned int plo[4], phi[4];
#pragma unroll
    for (int blk = 0; blk < 4; ++blk) {
      union { __bf16 h[2]; unsigned int u; } a, bb2;
      a.h[0] = (__bf16)sp[blk][0]; a.h[1] = (__bf16)sp[blk][1];
      bb2.h[0] = (__bf16)sp[blk][2]; bb2.h[1] = (__bf16)sp[blk][3];
      plo[blk] = a.u; phi[blk] = bb2.u;
    }
    // redistribute to PV B-fragment layout: pf[0] = chain A (k 0..31),
    // pf[1] = chain B (k 32..63)
    const int srcA = (g & 1) * 32 + q15;
    const int srcB = srcA + 16;
    const bool sel = (g >> 1) != 0;
    bf16x8 pf[2];
#pragma unroll
    for (int m = 0; m < 2; ++m) {
      const unsigned int lo0A = (unsigned int)__shfl((int)plo[2 * m], srcA);
      const unsigned int lo1A = (unsigned int)__shfl((int)plo[2 * m + 1], srcA);
      const unsigned int hi0A = (unsigned int)__shfl((int)phi[2 * m], srcA);
      const unsigned int hi1A = (unsigned int)__shfl((int)phi[2 * m + 1], srcA);
      const unsigned int lo0B = (unsigned int)__shfl((int)plo[2 * m], srcB);
      const unsigned int lo1B = (unsigned int)__shfl((int)plo[2 * m + 1], srcB);
      const unsigned int hi0B = (unsigned int)__shfl((int)phi[2 * m], srcB);
      const unsigned int hi1B = (unsigned int)__shfl((int)phi[2 * m + 1], srcB);
      union { unsigned int u[4]; bf16x8 v; } pk;
      pk.u[0] = sel ? lo1A : lo0A;
      pk.u[1] = sel ? hi1A : hi0A;
      pk.u[2] = sel ? lo1B : lo0B;
      pk.u[3] = sel ? hi1B : hi0B;
      pf[m] = pk.v;
    }
    // O^T += Vt * P^T — chain A accumulates k 0..31 (vf0), chain B k 32..63 (vf1)
    __builtin_amdgcn_s_setprio(1);
#pragma unroll
    for (int d = 0; d < 4; ++d) {
      const bf16x8 vf0 = *(const bf16x8*)(lvb + d * 1024 + oc0);
      const bf16x8 vf1 = *(const bf16x8*)(lvb + d * 1024 + oc1);
      otA[d] = __builtin_amdgcn_mfma_f32_16x16x32_bf16(vf0, pf[0], otA[d], 0, 0, 0);
      otB[d] = __builtin_amdgcn_mfma_f32_16x16x32_bf16(vf1, pf[1], otB[d], 0, 0, 0);
    }
    __builtin_amdgcn_s_setprio(0);

    if (phA && kt == tA) {  // phase switch: flush A, reset both chains
      STORE(tA);
      mrA = -1e20f; lrA = 0.f; mrB = -1e20f; lrB = 0.f;
#pragma unroll
      for (int d = 0; d < 4; ++d) { otA[d] = zf; otB[d] = zf; }
    }
    __syncthreads();
  }
  STORE(tB);
}

// ---------------- launch ----------------
extern "C" void kernel_launch(void* const* d_in, const int* in_sizes, int n_in,
                              void* d_out, int out_size, void* d_ws, size_t ws_size,
                              hipStream_t stream) {
  const float* X = (const float*)d_in[0];
  const int* pos = (const int*)d_in[1];
  const float* Wqkv = (const float*)d_in[2];
  const float* Wout = (const float*)d_in[3];
  char* ws = (char*)d_ws;
  unsigned short* xbf    = (unsigned short*)(ws + OFF_XBF);
  unsigned short* wqkvbf = (unsigned short*)(ws + OFF_WQKV);
  unsigned short* woutbf = (unsigned short*)(ws + OFF_WOUT);
  unsigned short* qb     = (unsigned short*)(ws + OFF_Q);
  unsigned short* kbuf   = (unsigned short*)(ws + OFF_K);
  unsigned short* vt     = (unsigned short*)(ws + OFF_VT);
  unsigned short* ob     = (unsigned short*)(ws + OFF_O);
  float2* rope           = (float2*)(ws + OFF_ROPE);

  prep_kernel<<<8192, 256, 0, stream>>>(X, Wqkv, Wout, pos, xbf, wqkvbf, woutbf, rope);
  gemm_kernel<0><<<dim3(NQKV / 128, MTOT / 128), 256, 0, stream>>>(
      xbf, wqkvbf, qb, kbuf, vt, rope, nullptr);
  attn_kernel<<<dim3(16, 32), 256, 0, stream>>>(qb, kbuf, vt, ob);
  gemm_kernel<1><<<dim3(DMODEL / 128, MTOT / 128), 256, 0, stream>>>(
      ob, woutbf, nullptr, nullptr, nullptr, nullptr, (float*)d_out);
}

// Round 8
// 156.616 us; speedup vs baseline: 1.1387x; 1.0519x over previous
//
#include <hip/hip_runtime.h>
#include <stdint.h>
#include <stddef.h>
#include <math.h>

#define DEVINL __device__ __forceinline__

typedef __attribute__((ext_vector_type(8))) __bf16 bf16x8;
typedef __attribute__((ext_vector_type(4))) float f32x4;
typedef __attribute__((ext_vector_type(4))) unsigned short us4;
typedef __attribute__((ext_vector_type(8))) unsigned short us8;
typedef __attribute__((ext_vector_type(4))) short short4v;  // K=16 MFMA A/B operand

typedef __attribute__((address_space(1))) unsigned int as1_uint;
typedef __attribute__((address_space(3))) unsigned int as3_uint;

constexpr int SEQ    = 2048;
constexpr int DMODEL = 1024;
constexpr int MTOT   = 4096;    // B*L
constexpr int NQKV   = 3072;
constexpr int DKH    = 64;

// workspace layout (bytes)
constexpr size_t OFF_XBF  = 0;                                      // 8 MiB
constexpr size_t OFF_WQKV = OFF_XBF  + (size_t)MTOT * DMODEL * 2;   // 6 MiB
constexpr size_t OFF_WOUT = OFF_WQKV + (size_t)NQKV * DMODEL * 2;   // 2 MiB
constexpr size_t OFF_Q    = OFF_WOUT + (size_t)DMODEL * DMODEL * 2; // 8 MiB
constexpr size_t OFF_K    = OFF_Q    + (size_t)MTOT * DMODEL * 2;   // 8 MiB
constexpr size_t OFF_VT   = OFF_K    + (size_t)MTOT * DMODEL * 2;   // 8 MiB
constexpr size_t OFF_O    = OFF_VT   + (size_t)MTOT * DMODEL * 2;   // 8 MiB
constexpr size_t OFF_ROPE = OFF_O    + (size_t)MTOT * DMODEL * 2;   // 1 MiB

// Q pre-scale: 1/sqrt(64) * log2(e) -> softmax runs in exp2 domain
constexpr float QSCALE = 0.125f * 1.4426950408889634f;

DEVINL unsigned short f2bf(float f) {
  unsigned int u = __float_as_uint(f);
  u += 0x7fffu + ((u >> 16) & 1u);
  return (unsigned short)(u >> 16);
}

DEVINL void gld_lds16(const unsigned short* g, unsigned short* s) {
  __builtin_amdgcn_global_load_lds((as1_uint*)g, (as3_uint*)s, 16, 0, 0);
}

// ---------------- prep: fp32->bf16 converts + rope table ----------------
__global__ __launch_bounds__(256) void prep_kernel(
    const float* __restrict__ X, const float* __restrict__ Wqkv,
    const float* __restrict__ Wout, const int* __restrict__ pos,
    unsigned short* __restrict__ xbf, unsigned short* __restrict__ wqkvbf,
    unsigned short* __restrict__ woutbf, float2* __restrict__ rope) {
  const int t = blockIdx.x * 256 + threadIdx.x;
  if (t < MTOT * 32) {  // rope table: (m, pair)
    const int m = t >> 5, ip = t & 31;
    const float freq = powf(10000.0f, -(float)(2 * ip) / 64.0f);
    const float ang = (float)pos[m] * freq;
    float sv, cv;
    sincosf(ang, &sv, &cv);
    rope[t] = make_float2(cv, sv);
  }
  const int NX = MTOT * DMODEL, NW1 = NQKV * DMODEL, NW2 = DMODEL * DMODEL;
  const int e = t * 4;
  const float* src;
  unsigned short* dst;
  if (e < NX) { src = X + e; dst = xbf + e; }
  else if (e < NX + NW1) { src = Wqkv + (e - NX); dst = wqkvbf + (e - NX); }
  else if (e < NX + NW1 + NW2) { src = Wout + (e - NX - NW1); dst = woutbf + (e - NX - NW1); }
  else return;
  const float4 v = *(const float4*)src;
  us4 o = { f2bf(v.x), f2bf(v.y), f2bf(v.z), f2bf(v.w) };
  *(us4*)dst = o;
}

// ---------------- GEMM: C[m][n] = sum_k A[m][k]*B[n][k], 128x128 tile ----------------
// MODE 0: A=Xbf, B=Wqkv -> RoPE epilogue, scatter Q (pre-scaled) / K row-major,
//         V transposed per head.
// MODE 1: A=Obf,  B=Wout -> fp32 store to d_out.
template <int MODE>
__global__ __launch_bounds__(256) void gemm_kernel(
    const unsigned short* __restrict__ A, const unsigned short* __restrict__ Bw,
    unsigned short* __restrict__ q_out, unsigned short* __restrict__ k_out,
    unsigned short* __restrict__ vt_out, const float2* __restrict__ rope,
    float* __restrict__ f_out) {
  constexpr int K = DMODEL;  // 1024
  __shared__ __align__(16) unsigned short As[128 * 32];
  __shared__ __align__(16) unsigned short Bs[128 * 32];
  const int tid = threadIdx.x;
  const int l = tid & 63, w = tid >> 6;
  const int g = l >> 4, l15 = l & 15;
  const int m0 = blockIdx.y * 128, n0 = blockIdx.x * 128;
  const int wm = w >> 1, wn = w & 1;

  // staging: per wave 1KiB per instr; lane chunk = base + l*16 bytes in LDS
  const unsigned short* ag = A  + (size_t)(m0 + w * 16 + (l >> 2)) * K + (l & 3) * 8;
  const unsigned short* bg = Bw + (size_t)(n0 + w * 16 + (l >> 2)) * K + (l & 3) * 8;
  unsigned short* as0 = As + w * 512;
  unsigned short* bs0 = Bs + w * 512;

  const f32x4 zf = {0.f, 0.f, 0.f, 0.f};
  f32x4 acc[4][4];
#pragma unroll
  for (int i = 0; i < 4; ++i)
#pragma unroll
    for (int j = 0; j < 4; ++j) acc[i][j] = zf;

  for (int kt = 0; kt < K / 32; ++kt) {
    const unsigned short* a0 = ag + kt * 32;
    const unsigned short* b0 = bg + kt * 32;
    gld_lds16(a0, as0);
    gld_lds16(a0 + (size_t)64 * K, as0 + 2048);
    gld_lds16(b0, bs0);
    gld_lds16(b0 + (size_t)64 * K, bs0 + 2048);
    __syncthreads();
    bf16x8 af[4], bf[4];
#pragma unroll
    for (int i = 0; i < 4; ++i)
      af[i] = *(const bf16x8*)(As + (wm * 64 + i * 16 + l15) * 32 + g * 8);
#pragma unroll
    for (int j = 0; j < 4; ++j)
      bf[j] = *(const bf16x8*)(Bs + (wn * 64 + j * 16 + l15) * 32 + g * 8);
#pragma unroll
    for (int i = 0; i < 4; ++i)
#pragma unroll
      for (int j = 0; j < 4; ++j)
        acc[i][j] = __builtin_amdgcn_mfma_f32_16x16x32_bf16(af[i], bf[j], acc[i][j], 0, 0, 0);
    __syncthreads();
  }

  if constexpr (MODE == 0) {
    const int region = n0 >> 10;  // 0=Q 1=K 2=V (128 | 1024 region boundaries)
    if (region <= 1) {
      unsigned short* outb = (region == 0) ? q_out : k_out;
      const float qs = (region == 0) ? QSCALE : 1.0f;
#pragma unroll
      for (int i = 0; i < 4; ++i) {
        const int mb = m0 + wm * 64 + i * 16 + g * 4;
#pragma unroll
        for (int j = 0; j < 4; ++j) {
          const int n = n0 + wn * 64 + j * 16 + l15;
          const int ncol = n & 1023;
          const int ip = (n & 63) >> 1;
          const float sgn = (n & 1) ? 1.f : -1.f;
#pragma unroll
          for (int r = 0; r < 4; ++r) {
            const int m = mb + r;
            const float v = acc[i][j][r];
            const float p = __shfl_xor(v, 1);  // partner column n^1
            const float2 cs = rope[m * 32 + ip];
            const float o = (v * cs.x + sgn * p * cs.y) * qs;
            outb[(size_t)m * DMODEL + ncol] = f2bf(o);
          }
        }
      }
    } else {  // V -> transposed per head: Vt[(b*1024 + h*64 + d)][l]
#pragma unroll
      for (int i = 0; i < 4; ++i) {
        const int mb = m0 + wm * 64 + i * 16 + g * 4;
        const int b = mb >> 11;
        const int lseq = mb & 2047;
#pragma unroll
        for (int j = 0; j < 4; ++j) {
          const int n = n0 + wn * 64 + j * 16 + l15;
          const int hd = n - 2048;
          us4 o = { f2bf(acc[i][j][0]), f2bf(acc[i][j][1]), f2bf(acc[i][j][2]), f2bf(acc[i][j][3]) };
          *(us4*)(vt_out + (size_t)(b * DMODEL + hd) * SEQ + lseq) = o;
        }
      }
    }
  } else {
#pragma unroll
    for (int i = 0; i < 4; ++i) {
      const int mb = m0 + wm * 64 + i * 16 + g * 4;
#pragma unroll
      for (int j = 0; j < 4; ++j) {
        const int n = n0 + wn * 64 + j * 16 + l15;
#pragma unroll
        for (int r = 0; r < 4; ++r) f_out[(size_t)(mb + r) * DMODEL + n] = acc[i][j][r];
      }
    }
  }
}

// ---------------- causal flash attention v8 ----------------
// Exact v2 structure (block j: sequential phases (31-j, j), 4 waves x 16
// q-rows, uniform 33 iterations, KVBLK=64 double-buffered, __syncthreads),
// but PV consumes P DIRECTLY from the QK^T output registers via K=16 MFMAs:
// QK^T C-layout (lane q15,g holds S[k=blk*16+4g+r][q15]) == the B-operand
// layout of v_mfma_f32_16x16x16_bf16 (col=lane&15, k=4*(lane>>4)+i). This
// deletes the 16-ds_bpermute P-repack from the critical path. V A-fragments
// are 16 ds_read_b64 (row 16*dt+q15, k = blk*16+4g, same XOR swizzle).
// lrun kept as per-lane partial; cross-lane reduced once per phase at STORE.
__global__ __launch_bounds__(256) void attn_kernel(
    const unsigned short* __restrict__ Qb, const unsigned short* __restrict__ Kb,
    const unsigned short* __restrict__ Vt, unsigned short* __restrict__ Ob) {
  __shared__ __align__(16) unsigned short kv[2][2][4096];  // [buf][K/V][64*64]
  __shared__ __align__(16) unsigned short Olds[4][16][72];
  const int tid = threadIdx.x;
  const int l = tid & 63, w = tid >> 6;
  const int g = l >> 4, q15 = l & 15;
  const int bh = blockIdx.y;
  const int b = bh >> 4, h = bh & 15;
  const int tA = 31 - blockIdx.x;   // long phase q-tile
  const int tB = blockIdx.x;        // short phase q-tile

  // Q fragments for both phases (16 q-rows per wave)
  const unsigned short* qpA = Qb + (size_t)(b * SEQ + tA * 64 + w * 16 + q15) * DMODEL + h * DKH + g * 8;
  const unsigned short* qpB = Qb + (size_t)(b * SEQ + tB * 64 + w * 16 + q15) * DMODEL + h * DKH + g * 8;
  const bf16x8 qA0 = *(const bf16x8*)qpA, qA1 = *(const bf16x8*)(qpA + 32);
  const bf16x8 qB0 = *(const bf16x8*)qpB, qB1 = *(const bf16x8*)(qpB + 32);
  const int qselA = tA * 64 + w * 16 + q15;
  const int qselB = tB * 64 + w * 16 + q15;

  // staging source (pre-swizzled): linear LDS slot o = tid*16 (+4096) holds
  // tile element (row = o>>7, colbyte = (o&127) ^ ((row&7)<<4))
  const int rS = tid >> 3;                                        // rows 0..31 (+32)
  const int cS = (((tid & 7) * 16) ^ ((rS & 7) << 4)) >> 1;       // element col
  const unsigned short* pKg = Kb + (size_t)(b * SEQ + rS) * DMODEL + h * DKH + cS;
  const unsigned short* pVg = Vt + (size_t)(b * DMODEL + h * DKH + rS) * SEQ + cS;

  // swizzled ds_read offsets (elements), reading row has row&7 == q15&7
  const int srow = (q15 & 7) << 4;
  const int oc0 = (srow ^ (g * 16)) >> 1;          // K frag: k-slice g*8..g*8+7
  const int oc1 = (srow ^ (g * 16 + 64)) >> 1;
  // V frag (K=16 A-operand): per blk, 8 bytes at col blk*32 + 8g
  int vc[4];
#pragma unroll
  for (int blk = 0; blk < 4; ++blk) vc[blk] = ((blk * 32 + 8 * g) ^ srow) >> 1;

  const f32x4 zf = {0.f, 0.f, 0.f, 0.f};
  float mrun = -1e30f, lrun = 0.f;   // lrun = PER-LANE partial row sum
  f32x4 ot[4];
#pragma unroll
  for (int d = 0; d < 4; ++d) ot[d] = zf;

  auto STAGE = [&](int bb, int k0) {
    unsigned short* lk = &kv[bb][0][0] + w * 512;  // wave-uniform base
    unsigned short* lv = &kv[bb][1][0] + w * 512;
    gld_lds16(pKg + (size_t)k0 * DMODEL, lk);
    gld_lds16(pKg + (size_t)(k0 + 32) * DMODEL, lk + 2048);
    gld_lds16(pVg + k0, lv);
    gld_lds16(pVg + (size_t)32 * SEQ + k0, lv + 2048);
  };

  auto STORE = [&](int qt) {
    float lr = lrun;
    lr += __shfl_xor(lr, 16);
    lr += __shfl_xor(lr, 32);
    const float inv = 1.0f / lr;
#pragma unroll
    for (int d = 0; d < 4; ++d) {
      us4 o = { f2bf(ot[d][0] * inv), f2bf(ot[d][1] * inv), f2bf(ot[d][2] * inv), f2bf(ot[d][3] * inv) };
      *(us4*)&Olds[w][q15][d * 16 + g * 4] = o;
    }
    __syncthreads();
    const int r = l >> 2;
    const int c = (l & 3) * 16;
    const us8 v0 = *(const us8*)&Olds[w][r][c];
    const us8 v1 = *(const us8*)&Olds[w][r][c + 8];
    unsigned short* ob = Ob + (size_t)(b * SEQ + qt * 64 + w * 16 + r) * DMODEL + h * DKH + c;
    *(us8*)ob = v0;
    *(us8*)(ob + 8) = v1;
  };

  STAGE(0, 0);
  __syncthreads();

  for (int i = 0; i < 33; ++i) {
    const int cur = i & 1;
    const bool phA = (i <= tA);
    const int kt = phA ? i : (i - tA - 1);
    if (i + 1 < 33) {
      const int kn = (i + 1 <= tA) ? (i + 1) : (i - tA);
      STAGE(cur ^ 1, kn * 64);
    }
    const bf16x8 qf0 = phA ? qA0 : qB0;
    const bf16x8 qf1 = phA ? qA1 : qB1;
    const bool domask = phA ? (kt == tA) : (kt == tB);
    const int qsel = phA ? qselA : qselB;
    const int kb0 = kt * 64;
    const unsigned short* lkb = &kv[cur][0][0] + q15 * 64;
    const unsigned short* lvb = &kv[cur][1][0] + q15 * 64;

    float sp[4][4];
    float mt = -1e30f;
#pragma unroll
    for (int blk = 0; blk < 4; ++blk) {
      const bf16x8 kf0 = *(const bf16x8*)(lkb + blk * 1024 + oc0);
      const bf16x8 kf1 = *(const bf16x8*)(lkb + blk * 1024 + oc1);
      f32x4 c = zf;
      c = __builtin_amdgcn_mfma_f32_16x16x32_bf16(kf0, qf0, c, 0, 0, 0);
      c = __builtin_amdgcn_mfma_f32_16x16x32_bf16(kf1, qf1, c, 0, 0, 0);
#pragma unroll
      for (int r = 0; r < 4; ++r) {
        float s = c[r];  // already in exp2 domain (Q pre-scaled)
        if (domask && (kb0 + blk * 16 + g * 4 + r > qsel)) s = -1e30f;
        sp[blk][r] = s;
        mt = fmaxf(mt, s);
      }
    }
    mt = fmaxf(mt, __shfl_xor(mt, 16));
    mt = fmaxf(mt, __shfl_xor(mt, 32));

    const bool defer = __all(mt - mrun <= 8.0f);
    float mnew, alpha;
    if (defer) { mnew = mrun; alpha = 1.0f; }
    else { mnew = fmaxf(mrun, mt); alpha = exp2f(mrun - mnew); }

    float rs = 0.f;
#pragma unroll
    for (int blk = 0; blk < 4; ++blk)
#pragma unroll
      for (int r = 0; r < 4; ++r) {
        const float p = exp2f(sp[blk][r] - mnew);
        sp[blk][r] = p;
        rs += p;
      }
    if (defer) {
      lrun += rs;                 // per-lane partial; cross-lane reduce at STORE
    } else {
      lrun = lrun * alpha + rs;
      mrun = mnew;
#pragma unroll
      for (int d = 0; d < 4; ++d) ot[d] *= alpha;
    }

    // P -> bf16 K=16 B-fragments IN-LANE (no shuffles): pfb[blk] holds
    // P[k=kb0+blk*16+4g+i][q15], i=0..3 — exactly the 16x16x16 B layout.
    short4v pfb[4];
#pragma unroll
    for (int blk = 0; blk < 4; ++blk) {
      union { __bf16 hh[4]; short4v v; } pk;
      pk.hh[0] = (__bf16)sp[blk][0];
      pk.hh[1] = (__bf16)sp[blk][1];
      pk.hh[2] = (__bf16)sp[blk][2];
      pk.hh[3] = (__bf16)sp[blk][3];
      pfb[blk] = pk.v;
    }

    // O^T[dt][q] += sum_blk Vt[16dt+q15][k(blk)] * P[k(blk)][q]  (K=16 MFMAs)
    __builtin_amdgcn_s_setprio(1);
#pragma unroll
    for (int dt = 0; dt < 4; ++dt) {
      const unsigned short* vrow = lvb + dt * 1024;
      f32x4 o = ot[dt];
#pragma unroll
      for (int blk = 0; blk < 4; ++blk) {
        const short4v vf = *(const short4v*)(vrow + vc[blk]);
        o = __builtin_amdgcn_mfma_f32_16x16x16bf16_1k(vf, pfb[blk], o, 0, 0, 0);
      }
      ot[dt] = o;
    }
    __builtin_amdgcn_s_setprio(0);

    if (phA && kt == tA) {  // phase switch: flush A, reset state
      STORE(tA);
      mrun = -1e30f; lrun = 0.f;
#pragma unroll
      for (int d = 0; d < 4; ++d) ot[d] = zf;
    }
    __syncthreads();
  }
  STORE(tB);
}

// ---------------- launch ----------------
extern "C" void kernel_launch(void* const* d_in, const int* in_sizes, int n_in,
                              void* d_out, int out_size, void* d_ws, size_t ws_size,
                              hipStream_t stream) {
  const float* X = (const float*)d_in[0];
  const int* pos = (const int*)d_in[1];
  const float* Wqkv = (const float*)d_in[2];
  const float* Wout = (const float*)d_in[3];
  char* ws = (char*)d_ws;
  unsigned short* xbf    = (unsigned short*)(ws + OFF_XBF);
  unsigned short* wqkvbf = (unsigned short*)(ws + OFF_WQKV);
  unsigned short* woutbf = (unsigned short*)(ws + OFF_WOUT);
  unsigned short* qb     = (unsigned short*)(ws + OFF_Q);
  unsigned short* kbuf   = (unsigned short*)(ws + OFF_K);
  unsigned short* vt     = (unsigned short*)(ws + OFF_VT);
  unsigned short* ob     = (unsigned short*)(ws + OFF_O);
  float2* rope           = (float2*)(ws + OFF_ROPE);

  prep_kernel<<<8192, 256, 0, stream>>>(X, Wqkv, Wout, pos, xbf, wqkvbf, woutbf, rope);
  gemm_kernel<0><<<dim3(NQKV / 128, MTOT / 128), 256, 0, stream>>>(
      xbf, wqkvbf, qb, kbuf, vt, rope, nullptr);
  attn_kernel<<<dim3(16, 32), 256, 0, stream>>>(qb, kbuf, vt, ob);
  gemm_kernel<1><<<dim3(DMODEL / 128, MTOT / 128), 256, 0, stream>>>(
      ob, woutbf, nullptr, nullptr, nullptr, nullptr, (float*)d_out);
}

// Round 9
// 148.691 us; speedup vs baseline: 1.1994x; 1.0533x over previous
//
#include <hip/hip_runtime.h>
#include <stdint.h>
#include <stddef.h>
#include <math.h>

#define DEVINL __device__ __forceinline__

typedef __attribute__((ext_vector_type(8))) __bf16 bf16x8;
typedef __attribute__((ext_vector_type(4))) float f32x4;
typedef __attribute__((ext_vector_type(4))) unsigned short us4;
typedef __attribute__((ext_vector_type(8))) unsigned short us8;
typedef __attribute__((ext_vector_type(4))) short short4v;  // K=16 MFMA A/B operand

typedef __attribute__((address_space(1))) unsigned int as1_uint;
typedef __attribute__((address_space(3))) unsigned int as3_uint;

constexpr int SEQ    = 2048;
constexpr int DMODEL = 1024;
constexpr int MTOT   = 4096;    // B*L
constexpr int NQKV   = 3072;
constexpr int DKH    = 64;

// workspace layout (bytes)
constexpr size_t OFF_XBF  = 0;                                      // 8 MiB
constexpr size_t OFF_WQKV = OFF_XBF  + (size_t)MTOT * DMODEL * 2;   // 6 MiB
constexpr size_t OFF_WOUT = OFF_WQKV + (size_t)NQKV * DMODEL * 2;   // 2 MiB
constexpr size_t OFF_Q    = OFF_WOUT + (size_t)DMODEL * DMODEL * 2; // 8 MiB
constexpr size_t OFF_K    = OFF_Q    + (size_t)MTOT * DMODEL * 2;   // 8 MiB
constexpr size_t OFF_VT   = OFF_K    + (size_t)MTOT * DMODEL * 2;   // 8 MiB
constexpr size_t OFF_O    = OFF_VT   + (size_t)MTOT * DMODEL * 2;   // 8 MiB
constexpr size_t OFF_ROPE = OFF_O    + (size_t)MTOT * DMODEL * 2;   // 1 MiB

// Q pre-scale: 1/sqrt(64) * log2(e) -> softmax runs in exp2 domain
constexpr float QSCALE = 0.125f * 1.4426950408889634f;

DEVINL unsigned short f2bf(float f) {
  unsigned int u = __float_as_uint(f);
  u += 0x7fffu + ((u >> 16) & 1u);
  return (unsigned short)(u >> 16);
}

DEVINL void gld_lds16(const unsigned short* g, unsigned short* s) {
  __builtin_amdgcn_global_load_lds((as1_uint*)g, (as3_uint*)s, 16, 0, 0);
}

// ---------------- prep: fp32->bf16 converts + rope table ----------------
__global__ __launch_bounds__(256) void prep_kernel(
    const float* __restrict__ X, const float* __restrict__ Wqkv,
    const float* __restrict__ Wout, const int* __restrict__ pos,
    unsigned short* __restrict__ xbf, unsigned short* __restrict__ wqkvbf,
    unsigned short* __restrict__ woutbf, float2* __restrict__ rope) {
  const int t = blockIdx.x * 256 + threadIdx.x;
  if (t < MTOT * 32) {  // rope table: (m, pair)
    const int m = t >> 5, ip = t & 31;
    const float freq = powf(10000.0f, -(float)(2 * ip) / 64.0f);
    const float ang = (float)pos[m] * freq;
    float sv, cv;
    sincosf(ang, &sv, &cv);
    rope[t] = make_float2(cv, sv);
  }
  const int NX = MTOT * DMODEL, NW1 = NQKV * DMODEL, NW2 = DMODEL * DMODEL;
  const int e = t * 4;
  const float* src;
  unsigned short* dst;
  if (e < NX) { src = X + e; dst = xbf + e; }
  else if (e < NX + NW1) { src = Wqkv + (e - NX); dst = wqkvbf + (e - NX); }
  else if (e < NX + NW1 + NW2) { src = Wout + (e - NX - NW1); dst = woutbf + (e - NX - NW1); }
  else return;
  const float4 v = *(const float4*)src;
  us4 o = { f2bf(v.x), f2bf(v.y), f2bf(v.z), f2bf(v.w) };
  *(us4*)dst = o;
}

// ---------------- GEMM: C[m][n] = sum_k A[m][k]*B[n][k], 128x128 tile ----------------
// MODE 0: A=Xbf, B=Wqkv -> RoPE epilogue, scatter Q (pre-scaled) / K row-major,
//         V transposed per head.
// MODE 1: A=Obf,  B=Wout -> fp32 store to d_out.
template <int MODE>
__global__ __launch_bounds__(256) void gemm_kernel(
    const unsigned short* __restrict__ A, const unsigned short* __restrict__ Bw,
    unsigned short* __restrict__ q_out, unsigned short* __restrict__ k_out,
    unsigned short* __restrict__ vt_out, const float2* __restrict__ rope,
    float* __restrict__ f_out) {
  constexpr int K = DMODEL;  // 1024
  __shared__ __align__(16) unsigned short As[128 * 32];
  __shared__ __align__(16) unsigned short Bs[128 * 32];
  const int tid = threadIdx.x;
  const int l = tid & 63, w = tid >> 6;
  const int g = l >> 4, l15 = l & 15;
  const int m0 = blockIdx.y * 128, n0 = blockIdx.x * 128;
  const int wm = w >> 1, wn = w & 1;

  // staging: per wave 1KiB per instr; lane chunk = base + l*16 bytes in LDS
  const unsigned short* ag = A  + (size_t)(m0 + w * 16 + (l >> 2)) * K + (l & 3) * 8;
  const unsigned short* bg = Bw + (size_t)(n0 + w * 16 + (l >> 2)) * K + (l & 3) * 8;
  unsigned short* as0 = As + w * 512;
  unsigned short* bs0 = Bs + w * 512;

  const f32x4 zf = {0.f, 0.f, 0.f, 0.f};
  f32x4 acc[4][4];
#pragma unroll
  for (int i = 0; i < 4; ++i)
#pragma unroll
    for (int j = 0; j < 4; ++j) acc[i][j] = zf;

  for (int kt = 0; kt < K / 32; ++kt) {
    const unsigned short* a0 = ag + kt * 32;
    const unsigned short* b0 = bg + kt * 32;
    gld_lds16(a0, as0);
    gld_lds16(a0 + (size_t)64 * K, as0 + 2048);
    gld_lds16(b0, bs0);
    gld_lds16(b0 + (size_t)64 * K, bs0 + 2048);
    __syncthreads();
    bf16x8 af[4], bf[4];
#pragma unroll
    for (int i = 0; i < 4; ++i)
      af[i] = *(const bf16x8*)(As + (wm * 64 + i * 16 + l15) * 32 + g * 8);
#pragma unroll
    for (int j = 0; j < 4; ++j)
      bf[j] = *(const bf16x8*)(Bs + (wn * 64 + j * 16 + l15) * 32 + g * 8);
#pragma unroll
    for (int i = 0; i < 4; ++i)
#pragma unroll
      for (int j = 0; j < 4; ++j)
        acc[i][j] = __builtin_amdgcn_mfma_f32_16x16x32_bf16(af[i], bf[j], acc[i][j], 0, 0, 0);
    __syncthreads();
  }

  if constexpr (MODE == 0) {
    const int region = n0 >> 10;  // 0=Q 1=K 2=V (128 | 1024 region boundaries)
    if (region <= 1) {
      unsigned short* outb = (region == 0) ? q_out : k_out;
      const float qs = (region == 0) ? QSCALE : 1.0f;
#pragma unroll
      for (int i = 0; i < 4; ++i) {
        const int mb = m0 + wm * 64 + i * 16 + g * 4;
#pragma unroll
        for (int j = 0; j < 4; ++j) {
          const int n = n0 + wn * 64 + j * 16 + l15;
          const int ncol = n & 1023;
          const int ip = (n & 63) >> 1;
          const float sgn = (n & 1) ? 1.f : -1.f;
#pragma unroll
          for (int r = 0; r < 4; ++r) {
            const int m = mb + r;
            const float v = acc[i][j][r];
            const float p = __shfl_xor(v, 1);  // partner column n^1
            const float2 cs = rope[m * 32 + ip];
            const float o = (v * cs.x + sgn * p * cs.y) * qs;
            outb[(size_t)m * DMODEL + ncol] = f2bf(o);
          }
        }
      }
    } else {  // V -> transposed per head: Vt[(b*1024 + h*64 + d)][l]
#pragma unroll
      for (int i = 0; i < 4; ++i) {
        const int mb = m0 + wm * 64 + i * 16 + g * 4;
        const int b = mb >> 11;
        const int lseq = mb & 2047;
#pragma unroll
        for (int j = 0; j < 4; ++j) {
          const int n = n0 + wn * 64 + j * 16 + l15;
          const int hd = n - 2048;
          us4 o = { f2bf(acc[i][j][0]), f2bf(acc[i][j][1]), f2bf(acc[i][j][2]), f2bf(acc[i][j][3]) };
          *(us4*)(vt_out + (size_t)(b * DMODEL + hd) * SEQ + lseq) = o;
        }
      }
    }
  } else {
#pragma unroll
    for (int i = 0; i < 4; ++i) {
      const int mb = m0 + wm * 64 + i * 16 + g * 4;
#pragma unroll
      for (int j = 0; j < 4; ++j) {
        const int n = n0 + wn * 64 + j * 16 + l15;
#pragma unroll
        for (int r = 0; r < 4; ++r) f_out[(size_t)(mb + r) * DMODEL + n] = acc[i][j][r];
      }
    }
  }
}

// ---------------- causal flash attention v9 ----------------
// v8 compute structure (pairing (31-j, j), 4 waves x 16 q-rows, uniform 33
// iterations, KVBLK=64 double-buffered, zero-shuffle K=16 PV) + XCD-AFFINITY
// BLOCK REMAP (T1): lid = x+16y round-robins XCDs (lid%8), so map
// xcd = lid&7, slot = lid>>3, bh = xcd*4 + (slot&3), j = slot>>2.
// All 16 blocks sharing one bh's K/V now land on ONE XCD; per-XCD L2 working
// set = 4 bh x (512KB K/V + 256KB Q) = 3MB < 4MB L2. Kills the 6x HBM
// over-fetch (97MB vs 16MB ideal) that made per-iteration staging drains
// HBM-latency-bound.
__global__ __launch_bounds__(256) void attn_kernel(
    const unsigned short* __restrict__ Qb, const unsigned short* __restrict__ Kb,
    const unsigned short* __restrict__ Vt, unsigned short* __restrict__ Ob) {
  __shared__ __align__(16) unsigned short kv[2][2][4096];  // [buf][K/V][64*64]
  __shared__ __align__(16) unsigned short Olds[4][16][72];
  const int tid = threadIdx.x;
  const int l = tid & 63, w = tid >> 6;
  const int g = l >> 4, q15 = l & 15;

  // XCD-affinity remap (bijective): blocks of one bh share lid mod 8
  const int lid = blockIdx.x + 16 * blockIdx.y;   // 0..511
  const int xcd = lid & 7;
  const int slot = lid >> 3;                      // 0..63
  const int bh = xcd * 4 + (slot & 3);            // 0..31
  const int j = slot >> 2;                        // 0..15

  const int b = bh >> 4, h = bh & 15;
  const int tA = 31 - j;            // long phase q-tile
  const int tB = j;                 // short phase q-tile

  // Q fragments for both phases (16 q-rows per wave)
  const unsigned short* qpA = Qb + (size_t)(b * SEQ + tA * 64 + w * 16 + q15) * DMODEL + h * DKH + g * 8;
  const unsigned short* qpB = Qb + (size_t)(b * SEQ + tB * 64 + w * 16 + q15) * DMODEL + h * DKH + g * 8;
  const bf16x8 qA0 = *(const bf16x8*)qpA, qA1 = *(const bf16x8*)(qpA + 32);
  const bf16x8 qB0 = *(const bf16x8*)qpB, qB1 = *(const bf16x8*)(qpB + 32);
  const int qselA = tA * 64 + w * 16 + q15;
  const int qselB = tB * 64 + w * 16 + q15;

  // staging source (pre-swizzled): linear LDS slot o = tid*16 (+4096) holds
  // tile element (row = o>>7, colbyte = (o&127) ^ ((row&7)<<4))
  const int rS = tid >> 3;                                        // rows 0..31 (+32)
  const int cS = (((tid & 7) * 16) ^ ((rS & 7) << 4)) >> 1;       // element col
  const unsigned short* pKg = Kb + (size_t)(b * SEQ + rS) * DMODEL + h * DKH + cS;
  const unsigned short* pVg = Vt + (size_t)(b * DMODEL + h * DKH + rS) * SEQ + cS;

  // swizzled ds_read offsets (elements), reading row has row&7 == q15&7
  const int srow = (q15 & 7) << 4;
  const int oc0 = (srow ^ (g * 16)) >> 1;          // K frag: k-slice g*8..g*8+7
  const int oc1 = (srow ^ (g * 16 + 64)) >> 1;
  // V frag (K=16 A-operand): per blk, 8 bytes at col blk*32 + 8g
  int vc[4];
#pragma unroll
  for (int blk = 0; blk < 4; ++blk) vc[blk] = ((blk * 32 + 8 * g) ^ srow) >> 1;

  const f32x4 zf = {0.f, 0.f, 0.f, 0.f};
  float mrun = -1e30f, lrun = 0.f;   // lrun = PER-LANE partial row sum
  f32x4 ot[4];
#pragma unroll
  for (int d = 0; d < 4; ++d) ot[d] = zf;

  auto STAGE = [&](int bb, int k0) {
    unsigned short* lk = &kv[bb][0][0] + w * 512;  // wave-uniform base
    unsigned short* lv = &kv[bb][1][0] + w * 512;
    gld_lds16(pKg + (size_t)k0 * DMODEL, lk);
    gld_lds16(pKg + (size_t)(k0 + 32) * DMODEL, lk + 2048);
    gld_lds16(pVg + k0, lv);
    gld_lds16(pVg + (size_t)32 * SEQ + k0, lv + 2048);
  };

  auto STORE = [&](int qt) {
    float lr = lrun;
    lr += __shfl_xor(lr, 16);
    lr += __shfl_xor(lr, 32);
    const float inv = 1.0f / lr;
#pragma unroll
    for (int d = 0; d < 4; ++d) {
      us4 o = { f2bf(ot[d][0] * inv), f2bf(ot[d][1] * inv), f2bf(ot[d][2] * inv), f2bf(ot[d][3] * inv) };
      *(us4*)&Olds[w][q15][d * 16 + g * 4] = o;
    }
    __syncthreads();
    const int r = l >> 2;
    const int c = (l & 3) * 16;
    const us8 v0 = *(const us8*)&Olds[w][r][c];
    const us8 v1 = *(const us8*)&Olds[w][r][c + 8];
    unsigned short* ob = Ob + (size_t)(b * SEQ + qt * 64 + w * 16 + r) * DMODEL + h * DKH + c;
    *(us8*)ob = v0;
    *(us8*)(ob + 8) = v1;
  };

  STAGE(0, 0);
  __syncthreads();

  for (int i = 0; i < 33; ++i) {
    const int cur = i & 1;
    const bool phA = (i <= tA);
    const int kt = phA ? i : (i - tA - 1);
    if (i + 1 < 33) {
      const int kn = (i + 1 <= tA) ? (i + 1) : (i - tA);
      STAGE(cur ^ 1, kn * 64);
    }
    const bf16x8 qf0 = phA ? qA0 : qB0;
    const bf16x8 qf1 = phA ? qA1 : qB1;
    const bool domask = phA ? (kt == tA) : (kt == tB);
    const int qsel = phA ? qselA : qselB;
    const int kb0 = kt * 64;
    const unsigned short* lkb = &kv[cur][0][0] + q15 * 64;
    const unsigned short* lvb = &kv[cur][1][0] + q15 * 64;

    float sp[4][4];
    float mt = -1e30f;
#pragma unroll
    for (int blk = 0; blk < 4; ++blk) {
      const bf16x8 kf0 = *(const bf16x8*)(lkb + blk * 1024 + oc0);
      const bf16x8 kf1 = *(const bf16x8*)(lkb + blk * 1024 + oc1);
      f32x4 c = zf;
      c = __builtin_amdgcn_mfma_f32_16x16x32_bf16(kf0, qf0, c, 0, 0, 0);
      c = __builtin_amdgcn_mfma_f32_16x16x32_bf16(kf1, qf1, c, 0, 0, 0);
#pragma unroll
      for (int r = 0; r < 4; ++r) {
        float s = c[r];  // already in exp2 domain (Q pre-scaled)
        if (domask && (kb0 + blk * 16 + g * 4 + r > qsel)) s = -1e30f;
        sp[blk][r] = s;
        mt = fmaxf(mt, s);
      }
    }
    mt = fmaxf(mt, __shfl_xor(mt, 16));
    mt = fmaxf(mt, __shfl_xor(mt, 32));

    const bool defer = __all(mt - mrun <= 8.0f);
    float mnew, alpha;
    if (defer) { mnew = mrun; alpha = 1.0f; }
    else { mnew = fmaxf(mrun, mt); alpha = exp2f(mrun - mnew); }

    float rs = 0.f;
#pragma unroll
    for (int blk = 0; blk < 4; ++blk)
#pragma unroll
      for (int r = 0; r < 4; ++r) {
        const float p = exp2f(sp[blk][r] - mnew);
        sp[blk][r] = p;
        rs += p;
      }
    if (defer) {
      lrun += rs;                 // per-lane partial; cross-lane reduce at STORE
    } else {
      lrun = lrun * alpha + rs;
      mrun = mnew;
#pragma unroll
      for (int d = 0; d < 4; ++d) ot[d] *= alpha;
    }

    // P -> bf16 K=16 B-fragments IN-LANE (no shuffles): pfb[blk] holds
    // P[k=kb0+blk*16+4g+i][q15], i=0..3 — exactly the 16x16x16 B layout.
    short4v pfb[4];
#pragma unroll
    for (int blk = 0; blk < 4; ++blk) {
      union { __bf16 hh[4]; short4v v; } pk;
      pk.hh[0] = (__bf16)sp[blk][0];
      pk.hh[1] = (__bf16)sp[blk][1];
      pk.hh[2] = (__bf16)sp[blk][2];
      pk.hh[3] = (__bf16)sp[blk][3];
      pfb[blk] = pk.v;
    }

    // O^T[dt][q] += sum_blk Vt[16dt+q15][k(blk)] * P[k(blk)][q]  (K=16 MFMAs)
    __builtin_amdgcn_s_setprio(1);
#pragma unroll
    for (int dt = 0; dt < 4; ++dt) {
      const unsigned short* vrow = lvb + dt * 1024;
      f32x4 o = ot[dt];
#pragma unroll
      for (int blk = 0; blk < 4; ++blk) {
        const short4v vf = *(const short4v*)(vrow + vc[blk]);
        o = __builtin_amdgcn_mfma_f32_16x16x16bf16_1k(vf, pfb[blk], o, 0, 0, 0);
      }
      ot[dt] = o;
    }
    __builtin_amdgcn_s_setprio(0);

    if (phA && kt == tA) {  // phase switch: flush A, reset state
      STORE(tA);
      mrun = -1e30f; lrun = 0.f;
#pragma unroll
      for (int d = 0; d < 4; ++d) ot[d] = zf;
    }
    __syncthreads();
  }
  STORE(tB);
}

// ---------------- launch ----------------
extern "C" void kernel_launch(void* const* d_in, const int* in_sizes, int n_in,
                              void* d_out, int out_size, void* d_ws, size_t ws_size,
                              hipStream_t stream) {
  const float* X = (const float*)d_in[0];
  const int* pos = (const int*)d_in[1];
  const float* Wqkv = (const float*)d_in[2];
  const float* Wout = (const float*)d_in[3];
  char* ws = (char*)d_ws;
  unsigned short* xbf    = (unsigned short*)(ws + OFF_XBF);
  unsigned short* wqkvbf = (unsigned short*)(ws + OFF_WQKV);
  unsigned short* woutbf = (unsigned short*)(ws + OFF_WOUT);
  unsigned short* qb     = (unsigned short*)(ws + OFF_Q);
  unsigned short* kbuf   = (unsigned short*)(ws + OFF_K);
  unsigned short* vt     = (unsigned short*)(ws + OFF_VT);
  unsigned short* ob     = (unsigned short*)(ws + OFF_O);
  float2* rope           = (float2*)(ws + OFF_ROPE);

  prep_kernel<<<8192, 256, 0, stream>>>(X, Wqkv, Wout, pos, xbf, wqkvbf, woutbf, rope);
  gemm_kernel<0><<<dim3(NQKV / 128, MTOT / 128), 256, 0, stream>>>(
      xbf, wqkvbf, qb, kbuf, vt, rope, nullptr);
  attn_kernel<<<dim3(16, 32), 256, 0, stream>>>(qb, kbuf, vt, ob);
  gemm_kernel<1><<<dim3(DMODEL / 128, MTOT / 128), 256, 0, stream>>>(
      ob, woutbf, nullptr, nullptr, nullptr, nullptr, (float*)d_out);
}

// Round 10
// 148.009 us; speedup vs baseline: 1.2049x; 1.0046x over previous
//
#include <hip/hip_runtime.h>
#include <stdint.h>
#include <stddef.h>
#include <math.h>

#define DEVINL __device__ __forceinline__

typedef __attribute__((ext_vector_type(8))) __bf16 bf16x8;
typedef __attribute__((ext_vector_type(4))) float f32x4;
typedef __attribute__((ext_vector_type(4))) unsigned short us4;
typedef __attribute__((ext_vector_type(8))) unsigned short us8;
typedef __attribute__((ext_vector_type(4))) short short4v;  // K=16 MFMA A/B operand

typedef __attribute__((address_space(1))) unsigned int as1_uint;
typedef __attribute__((address_space(3))) unsigned int as3_uint;

constexpr int SEQ    = 2048;
constexpr int DMODEL = 1024;
constexpr int MTOT   = 4096;    // B*L
constexpr int NQKV   = 3072;
constexpr int DKH    = 64;

// workspace layout (bytes)
constexpr size_t OFF_XBF  = 0;                                      // 8 MiB
constexpr size_t OFF_WQKV = OFF_XBF  + (size_t)MTOT * DMODEL * 2;   // 6 MiB
constexpr size_t OFF_WOUT = OFF_WQKV + (size_t)NQKV * DMODEL * 2;   // 2 MiB
constexpr size_t OFF_Q    = OFF_WOUT + (size_t)DMODEL * DMODEL * 2; // 8 MiB
constexpr size_t OFF_K    = OFF_Q    + (size_t)MTOT * DMODEL * 2;   // 8 MiB
constexpr size_t OFF_VT   = OFF_K    + (size_t)MTOT * DMODEL * 2;   // 8 MiB
constexpr size_t OFF_O    = OFF_VT   + (size_t)MTOT * DMODEL * 2;   // 8 MiB
constexpr size_t OFF_ROPE = OFF_O    + (size_t)MTOT * DMODEL * 2;   // 1 MiB

// Q pre-scale: 1/sqrt(64) * log2(e) -> softmax runs in exp2 domain
constexpr float QSCALE = 0.125f * 1.4426950408889634f;

DEVINL unsigned short f2bf(float f) {
  unsigned int u = __float_as_uint(f);
  u += 0x7fffu + ((u >> 16) & 1u);
  return (unsigned short)(u >> 16);
}

DEVINL void gld_lds16(const unsigned short* g, unsigned short* s) {
  __builtin_amdgcn_global_load_lds((as1_uint*)g, (as3_uint*)s, 16, 0, 0);
}

// ---------------- prep: fp32->bf16 converts + rope table ----------------
__global__ __launch_bounds__(256) void prep_kernel(
    const float* __restrict__ X, const float* __restrict__ Wqkv,
    const float* __restrict__ Wout, const int* __restrict__ pos,
    unsigned short* __restrict__ xbf, unsigned short* __restrict__ wqkvbf,
    unsigned short* __restrict__ woutbf, float2* __restrict__ rope) {
  const int t = blockIdx.x * 256 + threadIdx.x;
  if (t < MTOT * 32) {  // rope table: (m, pair)
    const int m = t >> 5, ip = t & 31;
    const float freq = powf(10000.0f, -(float)(2 * ip) / 64.0f);
    const float ang = (float)pos[m] * freq;
    float sv, cv;
    sincosf(ang, &sv, &cv);
    rope[t] = make_float2(cv, sv);
  }
  const int NX = MTOT * DMODEL, NW1 = NQKV * DMODEL, NW2 = DMODEL * DMODEL;
  const int e = t * 4;
  const float* src;
  unsigned short* dst;
  if (e < NX) { src = X + e; dst = xbf + e; }
  else if (e < NX + NW1) { src = Wqkv + (e - NX); dst = wqkvbf + (e - NX); }
  else if (e < NX + NW1 + NW2) { src = Wout + (e - NX - NW1); dst = woutbf + (e - NX - NW1); }
  else return;
  const float4 v = *(const float4*)src;
  us4 o = { f2bf(v.x), f2bf(v.y), f2bf(v.z), f2bf(v.w) };
  *(us4*)dst = o;
}

// ---------------- GEMM: C[m][n] = sum_k A[m][k]*B[n][k], 128x128 tile ----------------
// MODE 0: A=Xbf, B=Wqkv -> RoPE epilogue, scatter Q (pre-scaled) / K row-major,
//         V transposed per head.
// MODE 1: A=Obf,  B=Wout -> fp32 store to d_out.
template <int MODE>
__global__ __launch_bounds__(256) void gemm_kernel(
    const unsigned short* __restrict__ A, const unsigned short* __restrict__ Bw,
    unsigned short* __restrict__ q_out, unsigned short* __restrict__ k_out,
    unsigned short* __restrict__ vt_out, const float2* __restrict__ rope,
    float* __restrict__ f_out) {
  constexpr int K = DMODEL;  // 1024
  __shared__ __align__(16) unsigned short As[128 * 32];
  __shared__ __align__(16) unsigned short Bs[128 * 32];
  const int tid = threadIdx.x;
  const int l = tid & 63, w = tid >> 6;
  const int g = l >> 4, l15 = l & 15;
  const int m0 = blockIdx.y * 128, n0 = blockIdx.x * 128;
  const int wm = w >> 1, wn = w & 1;

  // staging: per wave 1KiB per instr; lane chunk = base + l*16 bytes in LDS
  const unsigned short* ag = A  + (size_t)(m0 + w * 16 + (l >> 2)) * K + (l & 3) * 8;
  const unsigned short* bg = Bw + (size_t)(n0 + w * 16 + (l >> 2)) * K + (l & 3) * 8;
  unsigned short* as0 = As + w * 512;
  unsigned short* bs0 = Bs + w * 512;

  const f32x4 zf = {0.f, 0.f, 0.f, 0.f};
  f32x4 acc[4][4];
#pragma unroll
  for (int i = 0; i < 4; ++i)
#pragma unroll
    for (int j = 0; j < 4; ++j) acc[i][j] = zf;

  for (int kt = 0; kt < K / 32; ++kt) {
    const unsigned short* a0 = ag + kt * 32;
    const unsigned short* b0 = bg + kt * 32;
    gld_lds16(a0, as0);
    gld_lds16(a0 + (size_t)64 * K, as0 + 2048);
    gld_lds16(b0, bs0);
    gld_lds16(b0 + (size_t)64 * K, bs0 + 2048);
    __syncthreads();
    bf16x8 af[4], bf[4];
#pragma unroll
    for (int i = 0; i < 4; ++i)
      af[i] = *(const bf16x8*)(As + (wm * 64 + i * 16 + l15) * 32 + g * 8);
#pragma unroll
    for (int j = 0; j < 4; ++j)
      bf[j] = *(const bf16x8*)(Bs + (wn * 64 + j * 16 + l15) * 32 + g * 8);
#pragma unroll
    for (int i = 0; i < 4; ++i)
#pragma unroll
      for (int j = 0; j < 4; ++j)
        acc[i][j] = __builtin_amdgcn_mfma_f32_16x16x32_bf16(af[i], bf[j], acc[i][j], 0, 0, 0);
    __syncthreads();
  }

  if constexpr (MODE == 0) {
    const int region = n0 >> 10;  // 0=Q 1=K 2=V (128 | 1024 region boundaries)
    if (region <= 1) {
      unsigned short* outb = (region == 0) ? q_out : k_out;
      const float qs = (region == 0) ? QSCALE : 1.0f;
#pragma unroll
      for (int i = 0; i < 4; ++i) {
        const int mb = m0 + wm * 64 + i * 16 + g * 4;
#pragma unroll
        for (int j = 0; j < 4; ++j) {
          const int n = n0 + wn * 64 + j * 16 + l15;
          const int ncol = n & 1023;
          const int ip = (n & 63) >> 1;
          const float sgn = (n & 1) ? 1.f : -1.f;
#pragma unroll
          for (int r = 0; r < 4; ++r) {
            const int m = mb + r;
            const float v = acc[i][j][r];
            const float p = __shfl_xor(v, 1);  // partner column n^1
            const float2 cs = rope[m * 32 + ip];
            const float o = (v * cs.x + sgn * p * cs.y) * qs;
            outb[(size_t)m * DMODEL + ncol] = f2bf(o);
          }
        }
      }
    } else {  // V -> transposed per head: Vt[(b*1024 + h*64 + d)][l]
#pragma unroll
      for (int i = 0; i < 4; ++i) {
        const int mb = m0 + wm * 64 + i * 16 + g * 4;
        const int b = mb >> 11;
        const int lseq = mb & 2047;
#pragma unroll
        for (int j = 0; j < 4; ++j) {
          const int n = n0 + wn * 64 + j * 16 + l15;
          const int hd = n - 2048;
          us4 o = { f2bf(acc[i][j][0]), f2bf(acc[i][j][1]), f2bf(acc[i][j][2]), f2bf(acc[i][j][3]) };
          *(us4*)(vt_out + (size_t)(b * DMODEL + hd) * SEQ + lseq) = o;
        }
      }
    }
  } else {
#pragma unroll
    for (int i = 0; i < 4; ++i) {
      const int mb = m0 + wm * 64 + i * 16 + g * 4;
#pragma unroll
      for (int j = 0; j < 4; ++j) {
        const int n = n0 + wn * 64 + j * 16 + l15;
#pragma unroll
        for (int r = 0; r < 4; ++r) f_out[(size_t)(mb + r) * DMODEL + n] = acc[i][j][r];
      }
    }
  }
}

// ---------------- causal flash attention v10 ----------------
// v9 (pairing (31-j,j), XCD-affinity remap, KVBLK=64 dbuf, zero-shuffle K=16
// PV) + K-SPLIT WAVE GROUPS: 8 waves/block (512 thr). Waves 0-3 (group lo)
// process k-cols 0..31 of each staged tile, waves 4-7 (hi) k-cols 32..63.
// Each group keeps its own online (m,l,O^T) over its disjoint k-subset
// (exactly commutative); merged in-LDS once per phase. Per-wave work halves,
// wave count doubles -> 16 waves/CU = 4 waves/SIMD (2x TLP) with zero block
// imbalance. Staging split: lo waves stage K, hi waves stage V (2 gld_lds
// each). m init = -1e20, mask = -1e30 so an all-masked group contributes
// exactly 0 (exp2(-1e30-(-1e20)) = 0; merge weight exp2(-1e20 - m*) = 0).
__global__ __launch_bounds__(512) void attn_kernel(
    const unsigned short* __restrict__ Qb, const unsigned short* __restrict__ Kb,
    const unsigned short* __restrict__ Vt, unsigned short* __restrict__ Ob) {
  __shared__ __align__(16) unsigned short kv[2][2][4096];  // 32 KiB [buf][K/V]
  __shared__ __align__(16) unsigned short Olds[4][16][72]; // 9 KiB
  __shared__ float mlo_s[4][16], llo_s[4][16];             // 512 B merge scratch
  const int tid = threadIdx.x;
  const int l = tid & 63, w = tid >> 6;   // w 0..7
  const int ws = w & 3;                   // q-subtile index
  const int gH = w >> 2;                  // k-half group: 0=lo (k 0..31), 1=hi
  const int g = l >> 4, q15 = l & 15;

  // XCD-affinity remap (bijective): blocks of one bh share lid mod 8
  const int lid = blockIdx.x + 16 * blockIdx.y;   // 0..511
  const int xcd = lid & 7;
  const int slot = lid >> 3;                      // 0..63
  const int bh = xcd * 4 + (slot & 3);            // 0..31
  const int j = slot >> 2;                        // 0..15

  const int b = bh >> 4, h = bh & 15;
  const int tA = 31 - j;            // long phase q-tile
  const int tB = j;                 // short phase q-tile

  // Q fragments for both phases (16 q-rows per wave-pair; lo/hi load same rows)
  const unsigned short* qpA = Qb + (size_t)(b * SEQ + tA * 64 + ws * 16 + q15) * DMODEL + h * DKH + g * 8;
  const unsigned short* qpB = Qb + (size_t)(b * SEQ + tB * 64 + ws * 16 + q15) * DMODEL + h * DKH + g * 8;
  const bf16x8 qA0 = *(const bf16x8*)qpA, qA1 = *(const bf16x8*)(qpA + 32);
  const bf16x8 qB0 = *(const bf16x8*)qpB, qB1 = *(const bf16x8*)(qpB + 32);
  const int qselA = tA * 64 + ws * 16 + q15;
  const int qselB = tB * 64 + ws * 16 + q15;

  // staging source (pre-swizzled): within each 256-thread stager group,
  // linear LDS slot o = stid*16 (+4096) holds tile element
  // (row = o>>7, colbyte = (o&127) ^ ((row&7)<<4))
  const int stid = tid & 255;
  const int rS = stid >> 3;                                       // rows 0..31 (+32)
  const int cS = (((stid & 7) * 16) ^ ((rS & 7) << 4)) >> 1;      // element col
  const unsigned short* pKg = Kb + (size_t)(b * SEQ + rS) * DMODEL + h * DKH + cS;
  const unsigned short* pVg = Vt + (size_t)(b * DMODEL + h * DKH + rS) * SEQ + cS;

  // swizzled ds_read offsets (elements), reading row has row&7 == q15&7
  const int srow = (q15 & 7) << 4;
  const int oc0 = (srow ^ (g * 16)) >> 1;          // K frag: d-slice g*8..g*8+7
  const int oc1 = (srow ^ (g * 16 + 64)) >> 1;
  // V frag (K=16 A-operand): per blk of this group, 8 bytes at col blk*32+8g
  const int blk0 = gH * 2;
  int vcg[2];
#pragma unroll
  for (int bi = 0; bi < 2; ++bi) vcg[bi] = (((blk0 + bi) * 32 + 8 * g) ^ srow) >> 1;

  const f32x4 zf = {0.f, 0.f, 0.f, 0.f};
  float mrun = -1e20f, lrun = 0.f;   // group-local online state; lrun per-lane
  f32x4 ot[4];
#pragma unroll
  for (int d = 0; d < 4; ++d) ot[d] = zf;

  auto STAGE = [&](int bb, int k0) {
    if (gH == 0) {  // lo waves stage the K tile
      unsigned short* lk = &kv[bb][0][0] + ws * 512;
      gld_lds16(pKg + (size_t)k0 * DMODEL, lk);
      gld_lds16(pKg + (size_t)(k0 + 32) * DMODEL, lk + 2048);
    } else {        // hi waves stage the V tile
      unsigned short* lv = &kv[bb][1][0] + ws * 512;
      gld_lds16(pVg + k0, lv);
      gld_lds16(pVg + (size_t)32 * SEQ + k0, lv + 2048);
    }
  };

  auto MERGE_STORE = [&](int qt, int scur) {
    // finish per-group l: reduce per-lane partials across g
    float lr = lrun;
    lr += __shfl_xor(lr, 16);
    lr += __shfl_xor(lr, 32);
    __syncthreads();  // A: all waves done reading kv[scur]
    float* sc = (float*)&kv[scur][0][0];  // 16 KiB scratch (f32[4096])
    const int base = ((ws * 16 + q15) * 4 + g) * 16;
    if (gH == 0) {
#pragma unroll
      for (int dt = 0; dt < 4; ++dt) *(f32x4*)&sc[base + dt * 4] = ot[dt];
      if (g == 0) { mlo_s[ws][q15] = mrun; llo_s[ws][q15] = lr; }
    }
    __syncthreads();  // B: lo's partials visible
    if (gH == 1) {
      const float mlo = mlo_s[ws][q15], llo = llo_s[ws][q15];
      const float mmax = fmaxf(mlo, mrun);
      const float wlo = exp2f(mlo - mmax), whi = exp2f(mrun - mmax);
      const float inv = 1.0f / (wlo * llo + whi * lr);
      const float fa = wlo * inv, fb = whi * inv;
#pragma unroll
      for (int dt = 0; dt < 4; ++dt) {
        const f32x4 olo = *(const f32x4*)&sc[base + dt * 4];
        const f32x4 of = olo * fa + ot[dt] * fb;
        us4 o = { f2bf(of[0]), f2bf(of[1]), f2bf(of[2]), f2bf(of[3]) };
        *(us4*)&Olds[ws][q15][dt * 16 + g * 4] = o;
      }
    }
    __syncthreads();  // C: Olds complete
    if (gH == 1) {    // transpose-read + coalesced store (hi waves only)
      const int r = l >> 2;
      const int c = (l & 3) * 16;
      const us8 v0 = *(const us8*)&Olds[ws][r][c];
      const us8 v1 = *(const us8*)&Olds[ws][r][c + 8];
      unsigned short* ob = Ob + (size_t)(b * SEQ + qt * 64 + ws * 16 + r) * DMODEL + h * DKH + c;
      *(us8*)ob = v0;
      *(us8*)(ob + 8) = v1;
    }
  };

  STAGE(0, 0);
  __syncthreads();

  for (int i = 0; i < 33; ++i) {
    const int cur = i & 1;
    const bool phA = (i <= tA);
    const int kt = phA ? i : (i - tA - 1);
    if (i + 1 < 33) {
      const int kn = (i + 1 <= tA) ? (i + 1) : (i - tA);
      STAGE(cur ^ 1, kn * 64);
    }
    const bf16x8 qf0 = phA ? qA0 : qB0;
    const bf16x8 qf1 = phA ? qA1 : qB1;
    const bool domask = phA ? (kt == tA) : (kt == tB);
    const int qsel = phA ? qselA : qselB;
    const int kb0 = kt * 64;
    const unsigned short* lkb = &kv[cur][0][0] + q15 * 64;
    const unsigned short* lvb = &kv[cur][1][0] + q15 * 64;

    // QK^T for this group's half (2 blks of 16 k-cols)
    float sp[2][4];
    float mt = -1e30f;
#pragma unroll
    for (int bi = 0; bi < 2; ++bi) {
      const int blk = blk0 + bi;
      const bf16x8 kf0 = *(const bf16x8*)(lkb + blk * 1024 + oc0);
      const bf16x8 kf1 = *(const bf16x8*)(lkb + blk * 1024 + oc1);
      f32x4 c = zf;
      c = __builtin_amdgcn_mfma_f32_16x16x32_bf16(kf0, qf0, c, 0, 0, 0);
      c = __builtin_amdgcn_mfma_f32_16x16x32_bf16(kf1, qf1, c, 0, 0, 0);
#pragma unroll
      for (int r = 0; r < 4; ++r) {
        float s = c[r];  // already in exp2 domain (Q pre-scaled)
        if (domask && (kb0 + blk * 16 + g * 4 + r > qsel)) s = -1e30f;
        sp[bi][r] = s;
        mt = fmaxf(mt, s);
      }
    }
    mt = fmaxf(mt, __shfl_xor(mt, 16));
    mt = fmaxf(mt, __shfl_xor(mt, 32));

    const bool defer = __all(mt - mrun <= 8.0f);
    float mnew, alpha;
    if (defer) { mnew = mrun; alpha = 1.0f; }
    else { mnew = fmaxf(mrun, mt); alpha = exp2f(mrun - mnew); }

    float rs = 0.f;
#pragma unroll
    for (int bi = 0; bi < 2; ++bi)
#pragma unroll
      for (int r = 0; r < 4; ++r) {
        const float p = exp2f(sp[bi][r] - mnew);
        sp[bi][r] = p;
        rs += p;
      }
    if (defer) {
      lrun += rs;                 // per-lane partial; reduced at merge
    } else {
      lrun = lrun * alpha + rs;
      mrun = mnew;
#pragma unroll
      for (int d = 0; d < 4; ++d) ot[d] *= alpha;
    }

    // P -> bf16 K=16 B-fragments in-lane (no shuffles)
    short4v pfb[2];
#pragma unroll
    for (int bi = 0; bi < 2; ++bi) {
      union { __bf16 hh[4]; short4v v; } pk;
      pk.hh[0] = (__bf16)sp[bi][0];
      pk.hh[1] = (__bf16)sp[bi][1];
      pk.hh[2] = (__bf16)sp[bi][2];
      pk.hh[3] = (__bf16)sp[bi][3];
      pfb[bi] = pk.v;
    }

    // O^T[dt][q] += sum_bi Vt[16dt+q15][k(blk0+bi)] * P[k][q]  (K=16 MFMAs)
    __builtin_amdgcn_s_setprio(1);
#pragma unroll
    for (int dt = 0; dt < 4; ++dt) {
      const unsigned short* vrow = lvb + dt * 1024;
      f32x4 o = ot[dt];
#pragma unroll
      for (int bi = 0; bi < 2; ++bi) {
        const short4v vf = *(const short4v*)(vrow + vcg[bi]);
        o = __builtin_amdgcn_mfma_f32_16x16x16bf16_1k(vf, pfb[bi], o, 0, 0, 0);
      }
      ot[dt] = o;
    }
    __builtin_amdgcn_s_setprio(0);

    if (phA && kt == tA) {  // phase switch: merge groups, flush A, reset
      MERGE_STORE(tA, cur);
      mrun = -1e20f; lrun = 0.f;
#pragma unroll
      for (int d = 0; d < 4; ++d) ot[d] = zf;
    }
    __syncthreads();
  }
  MERGE_STORE(tB, 0);   // last loop iter was i=32 -> cur=0, drained by loop barrier
}

// ---------------- launch ----------------
extern "C" void kernel_launch(void* const* d_in, const int* in_sizes, int n_in,
                              void* d_out, int out_size, void* d_ws, size_t ws_size,
                              hipStream_t stream) {
  const float* X = (const float*)d_in[0];
  const int* pos = (const int*)d_in[1];
  const float* Wqkv = (const float*)d_in[2];
  const float* Wout = (const float*)d_in[3];
  char* ws = (char*)d_ws;
  unsigned short* xbf    = (unsigned short*)(ws + OFF_XBF);
  unsigned short* wqkvbf = (unsigned short*)(ws + OFF_WQKV);
  unsigned short* woutbf = (unsigned short*)(ws + OFF_WOUT);
  unsigned short* qb     = (unsigned short*)(ws + OFF_Q);
  unsigned short* kbuf   = (unsigned short*)(ws + OFF_K);
  unsigned short* vt     = (unsigned short*)(ws + OFF_VT);
  unsigned short* ob     = (unsigned short*)(ws + OFF_O);
  float2* rope           = (float2*)(ws + OFF_ROPE);

  prep_kernel<<<8192, 256, 0, stream>>>(X, Wqkv, Wout, pos, xbf, wqkvbf, woutbf, rope);
  gemm_kernel<0><<<dim3(NQKV / 128, MTOT / 128), 256, 0, stream>>>(
      xbf, wqkvbf, qb, kbuf, vt, rope, nullptr);
  attn_kernel<<<dim3(16, 32), 512, 0, stream>>>(qb, kbuf, vt, ob);
  gemm_kernel<1><<<dim3(DMODEL / 128, MTOT / 128), 256, 0, stream>>>(
      ob, woutbf, nullptr, nullptr, nullptr, nullptr, (float*)d_out);
}